// Round 10
// baseline (926.890 us; speedup 1.0000x reference)
//
#include <hip/hip_runtime.h>
#include <math.h>

#define HD 128

typedef __attribute__((ext_vector_type(8))) short bf16x8;
typedef __attribute__((ext_vector_type(8))) unsigned short us8;
typedef __attribute__((ext_vector_type(4))) unsigned short us4;
typedef __attribute__((ext_vector_type(4))) float f32x4;

__device__ __forceinline__ float bf2f(unsigned short u) {
  union { unsigned int i; float f; } v; v.i = ((unsigned int)u) << 16; return v.f;
}
__device__ __forceinline__ unsigned short f2bf(float f) {
  union { float f; unsigned int i; } v; v.f = f;
  unsigned int u = v.i;
  u += 0x7FFFu + ((u >> 16) & 1u);
  return (unsigned short)(u >> 16);
}

__global__ void zero_f(float* p, int n) {
  int i = blockIdx.x * blockDim.x + threadIdx.x;
  if (i < n) p[i] = 0.f;
}

__global__ void zero_int(int* p, int n) {
  int stride = gridDim.x * blockDim.x;
  for (int i = blockIdx.x * blockDim.x + threadIdx.x; i < n; i += stride) p[i] = 0;
}

__global__ void encode_kernel(const int* __restrict__ x, const float* __restrict__ pe,
                              const float* __restrict__ ce, const float* __restrict__ le,
                              float* __restrict__ h, int n) {
  int total = n * HD;
  int stride = gridDim.x * blockDim.x;
  for (int idx = blockIdx.x * blockDim.x + threadIdx.x; idx < total; idx += stride) {
    int node = idx >> 7, c = idx & (HD - 1);
    int lv = x[node * 3 + 0]; lv = lv < 0 ? 0 : (lv > 999 ? 999 : lv);
    int ct = x[node * 3 + 1]; ct = ct < 0 ? 0 : (ct > 4 ? 4 : ct);
    int th = x[node * 3 + 2]; th = th < 0 ? 0 : (th > 4999 ? 4999 : th);
    h[idx] = ce[ct * HD + c] + le[lv * HD + c] + pe[th * HD + c];
  }
}

// split 7 [128][128] f32 weight mats into bf16 hi/lo in WAVE-TILED fragment layout:
// out[((cg*4+k4)*64 + lane)*8 + j] = W[k][c], c = cg*16+(lane&15), k = (k4*4+(lane>>4))*8+j
__global__ void prep_w(const float* __restrict__ cW1, const float* __restrict__ cW2,
                       const float* __restrict__ gW1,
                       unsigned short* __restrict__ whi, unsigned short* __restrict__ wlo) {
  int m = blockIdx.x;
  const float* W = (m < 3) ? cW1 + (size_t)m * HD * HD
                 : (m < 6) ? cW2 + (size_t)(m - 3) * HD * HD : gW1;
  unsigned short* oh = whi + (size_t)m * HD * HD;
  unsigned short* ol = wlo + (size_t)m * HD * HD;
  for (int i = threadIdx.x; i < HD * HD; i += 256) {
    int j = i & 7;
    int l = (i >> 3) & 63;
    int p = i >> 9;            // cg*4 + k4
    int cg = p >> 2, k4 = p & 3;
    int c = cg * 16 + (l & 15);
    int k = (k4 * 4 + (l >> 4)) * 8 + j;
    float f = W[k * HD + c];
    unsigned short hh = f2bf(f);
    oh[i] = hh;
    ol[i] = f2bf(f - bf2f(hh));
  }
}

// ---------------- CSR build (XCD-owned dst windows, see R8) ---------------------

__global__ void hist_kernel(const int* __restrict__ ei, int* deg, int E, int Wwin) {
  int pass = blockIdx.x & 7;
  int b = blockIdx.x >> 3;
  int tstride = (gridDim.x >> 3) * blockDim.x;
  for (int e = b * blockDim.x + threadIdx.x; e < E; e += tstride) {
    int d = ei[E + e];
    if (d / Wwin == pass) atomicAdd(&deg[d], 1);
  }
}

#define SCAN_BS 1024
__global__ void scan1_kernel(const int* __restrict__ deg, int* __restrict__ off,
                             int* __restrict__ bsum, int n) {
  __shared__ int sh[256];
  int b = blockIdx.x, t = threadIdx.x;
  int base = b * SCAN_BS + t * 4;
  int v[4];
#pragma unroll
  for (int j = 0; j < 4; j++) v[j] = (base + j < n) ? deg[base + j] : 0;
  int s = v[0] + v[1] + v[2] + v[3];
  sh[t] = s;
  __syncthreads();
  for (int o = 1; o < 256; o <<= 1) {
    int x = (t >= o) ? sh[t - o] : 0;
    __syncthreads();
    sh[t] += x;
    __syncthreads();
  }
  int excl = sh[t] - s;
  if (t == 255) bsum[b] = sh[255];
  int run = excl;
#pragma unroll
  for (int j = 0; j < 4; j++) {
    if (base + j < n) off[base + j] = run;
    run += v[j];
  }
}

__global__ void scan2_kernel(int* bsum, int nb) {
  __shared__ int sh[128];
  int t = threadIdx.x;
  int v = (t < nb) ? bsum[t] : 0;
  sh[t] = v;
  __syncthreads();
  for (int o = 1; o < 128; o <<= 1) {
    int x = (t >= o) ? sh[t - o] : 0;
    __syncthreads();
    sh[t] += x;
    __syncthreads();
  }
  if (t < nb) bsum[t] = sh[t] - v;
}

__global__ void scan3_kernel(int* off, int* cursor, const int* __restrict__ bsum,
                             int n, int E) {
  int idx = blockIdx.x * blockDim.x + threadIdx.x;
  int stride = gridDim.x * blockDim.x;
  for (int i = idx; i < n; i += stride) {
    int v = off[i] + bsum[i >> 10];
    off[i] = v;
    cursor[i] = v;
  }
  if (idx == 0) off[n] = E;
}

__global__ void fill_kernel(const int* __restrict__ ei, int* cursor, int* csr_src,
                            int E, int Wwin) {
  int pass = blockIdx.x & 7;
  int b = blockIdx.x >> 3;
  int tstride = (gridDim.x >> 3) * blockDim.x;
  for (int e = b * blockDim.x + threadIdx.x; e < E; e += tstride) {
    int d = ei[E + e];
    if (d / Wwin == pass) {
      int pos = atomicAdd(&cursor[d], 1);
      csr_src[pos] = ei[e];
    }
  }
}

// ---------------- fused gather + split-bf16 MFMA GEMM (64-row tile) ------------
// Per 64-row block: agg_i = f(h[i]) + sum_e f(h[src_e]) gathered into LDS as bf16
// hi/lo; then z = agg @ W^T + bias via Ah*Bh + Ah*Bl + Al*Bh; fused column stats.
// 33 KB LDS -> 4 blocks/CU (full occupancy for the latency-bound gather phase).
template<bool BN, bool STATS>
__global__ __launch_bounds__(512, 8)
void gemm_gather(const float* __restrict__ h, const int* __restrict__ off,
                 const int* __restrict__ src, const float* __restrict__ ab,
                 const unsigned short* __restrict__ Whi,
                 const unsigned short* __restrict__ Wlo,
                 const float* __restrict__ bias, float* __restrict__ outf,
                 float* __restrict__ stat, int Nn) {
  __shared__ unsigned short XsH[64 * HD];
  __shared__ unsigned short XsL[64 * HD];
  __shared__ float red[2 * HD];
  int t = threadIdx.x;
  long rowbase = (long)blockIdx.x * 64;
  int grp = t >> 5, lane = t & 31;

  float4 a4, b4;
  if (BN) {
    a4 = *(const float4*)(ab + lane * 4);
    b4 = *(const float4*)(ab + HD + lane * 4);
  }
#define APPLY_BN(v) if (BN) { \
    v.x = fmaxf(v.x * a4.x + b4.x, 0.f); \
    v.y = fmaxf(v.y * a4.y + b4.y, 0.f); \
    v.z = fmaxf(v.z * a4.z + b4.z, 0.f); \
    v.w = fmaxf(v.w * a4.w + b4.w, 0.f); }

  // gather phase: 16 groups x 32 lanes; 4 rows/group; 8-deep edge unroll
  for (int rr = 0; rr < 4; rr++) {
    int r = grp + rr * 16;
    long row = rowbase + r; if (row > Nn - 1) row = Nn - 1;
    int s0 = off[row], s1 = off[row + 1];
    float4 acc0 = *(const float4*)(h + row * HD + lane * 4);
    APPLY_BN(acc0);
    float4 acc1 = {0.f, 0.f, 0.f, 0.f};
    float4 acc2 = {0.f, 0.f, 0.f, 0.f};
    float4 acc3 = {0.f, 0.f, 0.f, 0.f};
    int e = s0;
    for (; e + 8 <= s1; e += 8) {
      int i0 = src[e], i1 = src[e + 1], i2 = src[e + 2], i3 = src[e + 3];
      int i4 = src[e + 4], i5 = src[e + 5], i6 = src[e + 6], i7 = src[e + 7];
      float4 v0 = *(const float4*)(h + (size_t)i0 * HD + lane * 4);
      float4 v1 = *(const float4*)(h + (size_t)i1 * HD + lane * 4);
      float4 v2 = *(const float4*)(h + (size_t)i2 * HD + lane * 4);
      float4 v3 = *(const float4*)(h + (size_t)i3 * HD + lane * 4);
      float4 v4 = *(const float4*)(h + (size_t)i4 * HD + lane * 4);
      float4 v5 = *(const float4*)(h + (size_t)i5 * HD + lane * 4);
      float4 v6 = *(const float4*)(h + (size_t)i6 * HD + lane * 4);
      float4 v7 = *(const float4*)(h + (size_t)i7 * HD + lane * 4);
      APPLY_BN(v0); APPLY_BN(v1); APPLY_BN(v2); APPLY_BN(v3);
      APPLY_BN(v4); APPLY_BN(v5); APPLY_BN(v6); APPLY_BN(v7);
      acc0.x += v0.x + v4.x; acc0.y += v0.y + v4.y; acc0.z += v0.z + v4.z; acc0.w += v0.w + v4.w;
      acc1.x += v1.x + v5.x; acc1.y += v1.y + v5.y; acc1.z += v1.z + v5.z; acc1.w += v1.w + v5.w;
      acc2.x += v2.x + v6.x; acc2.y += v2.y + v6.y; acc2.z += v2.z + v6.z; acc2.w += v2.w + v6.w;
      acc3.x += v3.x + v7.x; acc3.y += v3.y + v7.y; acc3.z += v3.z + v7.z; acc3.w += v3.w + v7.w;
    }
    for (; e < s1; e++) {
      int s = src[e];
      float4 v = *(const float4*)(h + (size_t)s * HD + lane * 4);
      APPLY_BN(v);
      acc0.x += v.x; acc0.y += v.y; acc0.z += v.z; acc0.w += v.w;
    }
    acc0.x += acc1.x + acc2.x + acc3.x;
    acc0.y += acc1.y + acc2.y + acc3.y;
    acc0.z += acc1.z + acc2.z + acc3.z;
    acc0.w += acc1.w + acc2.w + acc3.w;
    float f[4] = {acc0.x, acc0.y, acc0.z, acc0.w};
    us4 hi, lo;
#pragma unroll
    for (int j = 0; j < 4; j++) {
      unsigned short hh = f2bf(f[j]);
      hi[j] = hh;
      lo[j] = f2bf(f[j] - bf2f(hh));
    }
    int g8 = lane >> 1;
    int offl = r * HD + (((g8 ^ (r & 7)) << 3)) + (lane & 1) * 4;
    *(us4*)(XsH + offl) = hi;
    *(us4*)(XsL + offl) = lo;
  }
#undef APPLY_BN
  if (STATS && t < 2 * HD) red[t] = 0.f;
  __syncthreads();

  int w = t >> 6, l = t & 63;
  int lr = l & 15, lg = l >> 4;
  int wr = w & 3, wc = w >> 2;   // row quarter / col half

  f32x4 acc[4];
#pragma unroll
  for (int ct = 0; ct < 4; ct++) acc[ct] = (f32x4){0.f, 0.f, 0.f, 0.f};

  bf16x8 aH[4], aL[4];
  int arow = wr * 16 + lr;
#pragma unroll
  for (int k4 = 0; k4 < 4; k4++) {
    int kg = k4 * 4 + lg;
    int offa = arow * HD + (((kg ^ (arow & 7)) << 3));
    aH[k4] = *(bf16x8*)(XsH + offa);
    aL[k4] = *(bf16x8*)(XsL + offa);
  }
#pragma unroll
  for (int ct = 0; ct < 4; ct++) {
    int cg = wc * 4 + ct;
#pragma unroll
    for (int k4 = 0; k4 < 4; k4++) {
      int bo = (((cg << 2) + k4) * 64 + l) * 8;
      bf16x8 bH = *(const bf16x8*)(Whi + bo);
      bf16x8 bL = *(const bf16x8*)(Wlo + bo);
      acc[ct] = __builtin_amdgcn_mfma_f32_16x16x32_bf16(aH[k4], bH, acc[ct], 0, 0, 0);
      acc[ct] = __builtin_amdgcn_mfma_f32_16x16x32_bf16(aH[k4], bL, acc[ct], 0, 0, 0);
      acc[ct] = __builtin_amdgcn_mfma_f32_16x16x32_bf16(aL[k4], bH, acc[ct], 0, 0, 0);
    }
  }

  float s[4], ss[4];
#pragma unroll
  for (int ct = 0; ct < 4; ct++) { s[ct] = 0.f; ss[ct] = 0.f; }
#pragma unroll
  for (int jj = 0; jj < 4; jj++) {
    long row = rowbase + wr * 16 + lg * 4 + jj;
    bool ok = row < Nn;
#pragma unroll
    for (int ct = 0; ct < 4; ct++) {
      int col = (wc * 4 + ct) * 16 + lr;
      float v = acc[ct][jj] + bias[col];
      if (ok) {
        outf[row * HD + col] = v;
        if (STATS) { s[ct] += v; ss[ct] += v * v; }
      }
    }
  }
  if (STATS) {
#pragma unroll
    for (int ct = 0; ct < 4; ct++) {
      int col = (wc * 4 + ct) * 16 + lr;
      float sv = s[ct], sq = ss[ct];
      sv += __shfl_xor(sv, 16); sq += __shfl_xor(sq, 16);
      sv += __shfl_xor(sv, 32); sq += __shfl_xor(sq, 32);
      if (lg == 0) {
        atomicAdd(&red[col], sv);
        atomicAdd(&red[HD + col], sq);
      }
    }
    __syncthreads();
    float* st = stat + (blockIdx.x & 3) * 256;
    if (t < 2 * HD) atomicAdd(&st[t], red[t]);
  }
}

// ---------------- split-bf16 MFMA GEMM (contiguous input, 64-row tile) ---------
template<bool INBN, bool GATE, bool STATS>
__global__ __launch_bounds__(512, 8)
void gemm_split(const float* __restrict__ X, const unsigned short* __restrict__ Whi,
                const unsigned short* __restrict__ Wlo,
                const float* __restrict__ bias, const float* __restrict__ ab,
                const float* __restrict__ w2, float* __restrict__ outf,
                float* __restrict__ gate, float* __restrict__ stat, int Nn) {
  __shared__ unsigned short XsH[64 * HD];
  __shared__ unsigned short XsL[64 * HD];
  __shared__ float red[2 * HD];
  __shared__ float gred[64];
  int t = threadIdx.x;
  long rowbase = (long)blockIdx.x * 64;

#pragma unroll
  for (int it = 0; it < 4; it++) {
    int i = (t + it * 512) * 4;
    int r = i >> 7, k = i & (HD - 1);
    long row = rowbase + r; if (row > Nn - 1) row = Nn - 1;
    float4 v = *(const float4*)(X + row * HD + k);
    float f[4] = {v.x, v.y, v.z, v.w};
    if (INBN) {
#pragma unroll
      for (int j = 0; j < 4; j++)
        f[j] = fmaxf(f[j] * ab[k + j] + ab[HD + k + j], 0.f);
    }
    us4 hi, lo;
#pragma unroll
    for (int j = 0; j < 4; j++) {
      unsigned short hh = f2bf(f[j]);
      hi[j] = hh;
      lo[j] = f2bf(f[j] - bf2f(hh));
    }
    int g = k >> 3;
    int off = r * HD + ((((g ^ (r & 7)) << 3)) | (k & 7));
    *(us4*)(XsH + off) = hi;
    *(us4*)(XsL + off) = lo;
  }
  if (STATS && t < 2 * HD) red[t] = 0.f;
  if (GATE && t < 64) gred[t] = 0.f;
  __syncthreads();

  int w = t >> 6, l = t & 63;
  int lr = l & 15, lg = l >> 4;
  int wr = w & 3, wc = w >> 2;

  f32x4 acc[4];
#pragma unroll
  for (int ct = 0; ct < 4; ct++) acc[ct] = (f32x4){0.f, 0.f, 0.f, 0.f};

  bf16x8 aH[4], aL[4];
  int arow = wr * 16 + lr;
#pragma unroll
  for (int k4 = 0; k4 < 4; k4++) {
    int kg = k4 * 4 + lg;
    int off = arow * HD + (((kg ^ (arow & 7)) << 3));
    aH[k4] = *(bf16x8*)(XsH + off);
    aL[k4] = *(bf16x8*)(XsL + off);
  }
#pragma unroll
  for (int ct = 0; ct < 4; ct++) {
    int cg = wc * 4 + ct;
#pragma unroll
    for (int k4 = 0; k4 < 4; k4++) {
      int bo = (((cg << 2) + k4) * 64 + l) * 8;
      bf16x8 bH = *(const bf16x8*)(Whi + bo);
      bf16x8 bL = *(const bf16x8*)(Wlo + bo);
      acc[ct] = __builtin_amdgcn_mfma_f32_16x16x32_bf16(aH[k4], bH, acc[ct], 0, 0, 0);
      acc[ct] = __builtin_amdgcn_mfma_f32_16x16x32_bf16(aH[k4], bL, acc[ct], 0, 0, 0);
      acc[ct] = __builtin_amdgcn_mfma_f32_16x16x32_bf16(aL[k4], bH, acc[ct], 0, 0, 0);
    }
  }

  if (GATE) {
    // row dot: sum over this wave's col half, then cross-wave reduce via LDS
#pragma unroll
    for (int jj = 0; jj < 4; jj++) {
      float p = 0.f;
#pragma unroll
      for (int ct = 0; ct < 4; ct++) {
        int col = (wc * 4 + ct) * 16 + lr;
        float v = fmaxf(acc[ct][jj] + bias[col], 0.f);
        p += v * w2[col];
      }
      p += __shfl_xor(p, 1);
      p += __shfl_xor(p, 2);
      p += __shfl_xor(p, 4);
      p += __shfl_xor(p, 8);
      if (lr == 0) atomicAdd(&gred[wr * 16 + lg * 4 + jj], p);
    }
    __syncthreads();
    if (t < 64 && rowbase + t < Nn) gate[rowbase + t] = gred[t];
  } else {
    float s[4], ss[4];
#pragma unroll
    for (int ct = 0; ct < 4; ct++) { s[ct] = 0.f; ss[ct] = 0.f; }
#pragma unroll
    for (int jj = 0; jj < 4; jj++) {
      long row = rowbase + wr * 16 + lg * 4 + jj;
      bool ok = row < Nn;
#pragma unroll
      for (int ct = 0; ct < 4; ct++) {
        int col = (wc * 4 + ct) * 16 + lr;
        float v = acc[ct][jj] + bias[col];
        if (ok) {
          outf[row * HD + col] = v;
          if (STATS) { s[ct] += v; ss[ct] += v * v; }
        }
      }
    }
    if (STATS) {
#pragma unroll
      for (int ct = 0; ct < 4; ct++) {
        int col = (wc * 4 + ct) * 16 + lr;
        float sv = s[ct], sq = ss[ct];
        sv += __shfl_xor(sv, 16); sq += __shfl_xor(sq, 16);
        sv += __shfl_xor(sv, 32); sq += __shfl_xor(sq, 32);
        if (lg == 0) {
          atomicAdd(&red[col], sv);
          atomicAdd(&red[HD + col], sq);
        }
      }
      __syncthreads();
      float* st = stat + (blockIdx.x & 3) * 256;
      if (t < 2 * HD) atomicAdd(&st[t], red[t]);
    }
  }
}

__global__ void finalize_kernel(const float* __restrict__ stat, const float* __restrict__ g,
                                const float* __restrict__ be, float* ab, float inv_n) {
  int c = threadIdx.x;
  float s = stat[c] + stat[256 + c] + stat[512 + c] + stat[768 + c];
  float sq = stat[HD + c] + stat[256 + HD + c] + stat[512 + HD + c] + stat[768 + HD + c];
  float mean = s * inv_n;
  float var = sq * inv_n - mean * mean;
  float inv = rsqrtf(var + 1e-5f);
  float a = inv * g[c];
  ab[c] = a;
  ab[HD + c] = be[c] - mean * a;
}

__global__ void finalize1_kernel(const float* __restrict__ stat, const float* __restrict__ g,
                                 const float* __restrict__ be, float* ab, float inv_n) {
  int c = threadIdx.x;
  float mean = stat[c] * inv_n;
  float var = stat[HD + c] * inv_n - mean * mean;
  float inv = rsqrtf(var + 1e-5f);
  float a = inv * g[c];
  ab[c] = a;
  ab[HD + c] = be[c] - mean * a;
}

__global__ void bound_kernel(const int* __restrict__ batch, int* gs, int N, int G) {
  int i = blockIdx.x * blockDim.x + threadIdx.x;
  if (i >= N) return;
  int b = batch[i];
  int prev = (i == 0) ? -1 : batch[i - 1];
  for (int g = prev + 1; g <= b; g++) gs[g] = i;
  if (i == N - 1)
    for (int g = b + 1; g <= G; g++) gs[g] = N;
}

__global__ void fused_pool(const float* __restrict__ h, const float* __restrict__ gate,
                           const int* __restrict__ gs, const float* __restrict__ ab,
                           float* __restrict__ pooled) {
  int g = blockIdx.x;
  int t = threadIdx.x;
  int s0 = gs[g], s1 = gs[g + 1];
  if (s0 >= s1) { pooled[(size_t)g * HD + t] = 0.f; return; }
  __shared__ float red[HD];
  float m = -INFINITY;
  for (int i = s0 + t; i < s1; i += HD) m = fmaxf(m, gate[i]);
  red[t] = m;
  __syncthreads();
  for (int o = 64; o > 0; o >>= 1) {
    if (t < o) red[t] = fmaxf(red[t], red[t + o]);
    __syncthreads();
  }
  m = red[0];
  __syncthreads();
  float s = 0.f;
  for (int i = s0 + t; i < s1; i += HD) s += expf(gate[i] - m);
  red[t] = s;
  __syncthreads();
  for (int o = 64; o > 0; o >>= 1) {
    if (t < o) red[t] += red[t + o];
    __syncthreads();
  }
  float inv = 1.f / red[0];
  float a = ab[t], b = ab[HD + t];
  float acc = 0.f;
  int i = s0;
  for (; i + 4 <= s1; i += 4) {
    float al0 = expf(gate[i] - m);
    float al1 = expf(gate[i + 1] - m);
    float al2 = expf(gate[i + 2] - m);
    float al3 = expf(gate[i + 3] - m);
    float v0 = fmaxf(h[(size_t)(i + 0) * HD + t] * a + b, 0.f);
    float v1 = fmaxf(h[(size_t)(i + 1) * HD + t] * a + b, 0.f);
    float v2 = fmaxf(h[(size_t)(i + 2) * HD + t] * a + b, 0.f);
    float v3 = fmaxf(h[(size_t)(i + 3) * HD + t] * a + b, 0.f);
    acc += al0 * v0 + al1 * v1 + al2 * v2 + al3 * v3;
  }
  for (; i < s1; i++) {
    float al = expf(gate[i] - m);
    float v = fmaxf(h[(size_t)i * HD + t] * a + b, 0.f);
    acc += al * v;
  }
  pooled[(size_t)g * HD + t] = acc * inv;
}

// f32 classifier GEMM: zc[G x 128] = pooled @ W + bias
__global__ __launch_bounds__(256, 4)
void gemm_f32(const float* __restrict__ X, const float* __restrict__ W,
              const float* __restrict__ bias, float* __restrict__ out, int Nn) {
  __shared__ float XsT[32][132];
  __shared__ float Ws[32][HD];
  int t = threadIdx.x;
  int r0 = (t >> 4) * 8;
  int c0 = (t & 15) * 8;
  long rowbase = (long)blockIdx.x * 128;

  float acc[8][8];
#pragma unroll
  for (int ci = 0; ci < 8; ci++) {
    float bv = bias[c0 + ci];
#pragma unroll
    for (int ri = 0; ri < 8; ri++) acc[ri][ci] = bv;
  }

  int sr = t >> 1;
  int hf = t & 1;
  long srow = rowbase + sr; if (srow > Nn - 1) srow = Nn - 1;
  const float* xrow = X + srow * HD;

  for (int k0 = 0; k0 < HD; k0 += 32) {
    __syncthreads();
#pragma unroll
    for (int j = 0; j < 4; j++) {
      int i = j * 1024 + t * 4;
      int kk = i >> 7, c = i & (HD - 1);
      *(float4*)&Ws[kk][c] = *(const float4*)&W[(size_t)(k0 + kk) * HD + c];
    }
#pragma unroll
    for (int j = 0; j < 4; j++) {
      int kc = k0 + hf * 16 + j * 4;
      float4 v = *(const float4*)&xrow[kc];
      int kl = hf * 16 + j * 4;
      XsT[kl + 0][sr] = v.x;
      XsT[kl + 1][sr] = v.y;
      XsT[kl + 2][sr] = v.z;
      XsT[kl + 3][sr] = v.w;
    }
    __syncthreads();
#pragma unroll 8
    for (int kk = 0; kk < 32; kk++) {
      float4 a0 = *(float4*)&XsT[kk][r0];
      float4 a1 = *(float4*)&XsT[kk][r0 + 4];
      float4 b0 = *(float4*)&Ws[kk][c0];
      float4 b1 = *(float4*)&Ws[kk][c0 + 4];
      float ar[8] = {a0.x, a0.y, a0.z, a0.w, a1.x, a1.y, a1.z, a1.w};
      float bc[8] = {b0.x, b0.y, b0.z, b0.w, b1.x, b1.y, b1.z, b1.w};
#pragma unroll
      for (int ri = 0; ri < 8; ri++)
#pragma unroll
        for (int ci = 0; ci < 8; ci++) acc[ri][ci] += ar[ri] * bc[ci];
    }
  }

#pragma unroll
  for (int ri = 0; ri < 8; ri++) {
    long row = rowbase + r0 + ri;
    if (row < Nn) {
      float4 o0 = {acc[ri][0], acc[ri][1], acc[ri][2], acc[ri][3]};
      float4 o1 = {acc[ri][4], acc[ri][5], acc[ri][6], acc[ri][7]};
      *(float4*)&out[row * HD + c0] = o0;
      *(float4*)&out[row * HD + c0 + 4] = o1;
    }
  }
}

__global__ void stats_f32(const float* __restrict__ z, float* stat, int n) {
  int c = threadIdx.x & (HD - 1);
  int rg = threadIdx.x >> 7;
  float s = 0.f, ss = 0.f;
  for (int r = blockIdx.x * 2 + rg; r < n; r += gridDim.x * 2) {
    float v = z[(size_t)r * HD + c];
    s += v; ss += v * v;
  }
  __shared__ float S[2][HD], SS[2][HD];
  S[rg][c] = s; SS[rg][c] = ss;
  __syncthreads();
  if (threadIdx.x < HD) {
    atomicAdd(&stat[c], S[0][c] + S[1][c]);
    atomicAdd(&stat[HD + c], SS[0][c] + SS[1][c]);
  }
}

__global__ void cls_out_kernel(const float* __restrict__ zc, const float* __restrict__ ab,
                               const float* __restrict__ W2, const float* __restrict__ b2,
                               float* out, int G) {
  int row = blockIdx.x;
  int t = threadIdx.x;
  float v0 = fmaxf(zc[(size_t)row * HD + t] * ab[t] + ab[HD + t], 0.f);
  float v1 = fmaxf(zc[(size_t)row * HD + 64 + t] * ab[64 + t] + ab[HD + 64 + t], 0.f);
  for (int o = 0; o < 10; o++) {
    float p = v0 * W2[t * 10 + o] + v1 * W2[(64 + t) * 10 + o];
#pragma unroll
    for (int s = 32; s > 0; s >>= 1) p += __shfl_down(p, s);
    if (t == 0) out[row * 10 + o] = p + b2[o];
  }
}

extern "C" void kernel_launch(void* const* d_in, const int* in_sizes, int n_in,
                              void* d_out, int out_size, void* d_ws, size_t ws_size,
                              hipStream_t stream) {
  const int* x     = (const int*)d_in[0];
  const int* ei    = (const int*)d_in[1];
  const int* batch = (const int*)d_in[2];
  const float* pe  = (const float*)d_in[4];
  const float* ce  = (const float*)d_in[5];
  const float* le  = (const float*)d_in[6];
  const float* cW1 = (const float*)d_in[7];
  const float* cb1 = (const float*)d_in[8];
  const float* cg1 = (const float*)d_in[9];
  const float* cbe1= (const float*)d_in[10];
  const float* cW2 = (const float*)d_in[11];
  const float* cb2 = (const float*)d_in[12];
  const float* ngm = (const float*)d_in[13];
  const float* nbe = (const float*)d_in[14];
  const float* gW1 = (const float*)d_in[15];
  const float* gb1 = (const float*)d_in[16];
  const float* gW2 = (const float*)d_in[17];
  const float* clW1= (const float*)d_in[19];
  const float* clb1= (const float*)d_in[20];
  const float* clg = (const float*)d_in[21];
  const float* clbe= (const float*)d_in[22];
  const float* clW2= (const float*)d_in[23];
  const float* clb2= (const float*)d_in[24];

  int N = in_sizes[2];
  int E = in_sizes[1] / 2;
  int G = out_size / 10;

  float* buf0   = (float*)d_ws;              // h (f32)
  float* buf1   = buf0 + (size_t)N * HD;     // z (f32)
  float* pooled = buf1 + (size_t)N * HD;     // G x 128
  float* gate   = pooled + (size_t)G * HD;   // N
  float* zc     = gate + N;                  // G x 128
  float* stats  = zc + (size_t)G * HD;       // 7 x 1024
  float* ab     = stats + 7 * 1024;          // 7 x 256
  unsigned short* whi = (unsigned short*)(ab + 7 * 256);  // 7 x 128 x 128 bf16
  unsigned short* wlo = whi + 7 * HD * HD;
  int* csr_off  = (int*)(wlo + 7 * HD * HD); // N+1
  int* cursor   = csr_off + (N + 1);         // N
  int* bsum     = cursor + N;                // 128
  int* gs       = bsum + 128;                // G+1
  int* csr_src  = gs + (G + 1);              // E

  float* out = (float*)d_out;
  int gemmBlocks = (N + 63) / 64;
  int Wwin = (N + 7) / 8;

  zero_f<<<28, 256, 0, stream>>>(stats, 7 * 1024);
  encode_kernel<<<2048, 256, 0, stream>>>(x, pe, ce, le, buf0, N);
  prep_w<<<7, 256, 0, stream>>>(cW1, cW2, gW1, whi, wlo);

  // CSR build (XCD-owned dst windows; reused by all 3 layers)
  int nb = (N + SCAN_BS - 1) / SCAN_BS;
  zero_int<<<256, 256, 0, stream>>>(cursor, N);
  hist_kernel<<<2048, 256, 0, stream>>>(ei, cursor, E, Wwin);
  scan1_kernel<<<nb, 256, 0, stream>>>(cursor, csr_off, bsum, N);
  scan2_kernel<<<1, 128, 0, stream>>>(bsum, nb);
  scan3_kernel<<<256, 256, 0, stream>>>(csr_off, cursor, bsum, N, E);
  fill_kernel<<<2048, 256, 0, stream>>>(ei, cursor, csr_src, E, Wwin);
  bound_kernel<<<(N + 255) / 256, 256, 0, stream>>>(batch, gs, N, G);

  for (int l = 0; l < 3; l++) {
    float* abPrev = ab + (l - 1) * 512 + 256;
    if (l == 0)
      gemm_gather<false, true><<<gemmBlocks, 512, 0, stream>>>(
          buf0, csr_off, csr_src, nullptr,
          whi + (size_t)l * HD * HD, wlo + (size_t)l * HD * HD,
          cb1 + l * HD, buf1, stats + l * 2048, N);
    else
      gemm_gather<true, true><<<gemmBlocks, 512, 0, stream>>>(
          buf0, csr_off, csr_src, abPrev,
          whi + (size_t)l * HD * HD, wlo + (size_t)l * HD * HD,
          cb1 + l * HD, buf1, stats + l * 2048, N);
    finalize_kernel<<<1, 128, 0, stream>>>(stats + l * 2048, cg1 + l * HD, cbe1 + l * HD,
                                           ab + l * 512, 1.f / N);
    gemm_split<true, false, true><<<gemmBlocks, 512, 0, stream>>>(
        buf1, whi + (size_t)(3 + l) * HD * HD, wlo + (size_t)(3 + l) * HD * HD,
        cb2 + l * HD, ab + l * 512, nullptr, buf0, nullptr, stats + l * 2048 + 1024, N);
    finalize_kernel<<<1, 128, 0, stream>>>(stats + l * 2048 + 1024, ngm + l * HD, nbe + l * HD,
                                           ab + l * 512 + 256, 1.f / N);
  }

  const float* abFin = ab + 2 * 512 + 256;
  gemm_split<true, true, false><<<gemmBlocks, 512, 0, stream>>>(
      buf0, whi + (size_t)6 * HD * HD, wlo + (size_t)6 * HD * HD,
      gb1, abFin, gW2, nullptr, gate, nullptr, N);
  fused_pool<<<G, HD, 0, stream>>>(buf0, gate, gs, abFin, pooled);

  // classifier tail in f32
  gemm_f32<<<(G + 127) / 128, 256, 0, stream>>>(pooled, clW1, clb1, zc, G);
  stats_f32<<<64, 256, 0, stream>>>(zc, stats + 6 * 1024, G);
  finalize1_kernel<<<1, 128, 0, stream>>>(stats + 6 * 1024, clg, clbe, ab + 6 * 256, 1.f / G);
  cls_out_kernel<<<G, 64, 0, stream>>>(zc, ab + 6 * 256, clW2, clb2, out, G);
}

// Round 11
// 887.538 us; speedup vs baseline: 1.0443x; 1.0443x over previous
//
#include <hip/hip_runtime.h>
#include <math.h>

#define HD 128

typedef __attribute__((ext_vector_type(8))) short bf16x8;
typedef __attribute__((ext_vector_type(8))) unsigned short us8;
typedef __attribute__((ext_vector_type(4))) unsigned short us4;
typedef __attribute__((ext_vector_type(4))) float f32x4;

__device__ __forceinline__ float bf2f(unsigned short u) {
  union { unsigned int i; float f; } v; v.i = ((unsigned int)u) << 16; return v.f;
}
__device__ __forceinline__ unsigned short f2bf(float f) {
  union { float f; unsigned int i; } v; v.f = f;
  unsigned int u = v.i;
  u += 0x7FFFu + ((u >> 16) & 1u);
  return (unsigned short)(u >> 16);
}

__global__ void zero_f(float* p, int n) {
  int i = blockIdx.x * blockDim.x + threadIdx.x;
  if (i < n) p[i] = 0.f;
}

__global__ void zero_int(int* p, int n) {
  int stride = gridDim.x * blockDim.x;
  for (int i = blockIdx.x * blockDim.x + threadIdx.x; i < n; i += stride) p[i] = 0;
}

__global__ void encode_kernel(const int* __restrict__ x, const float* __restrict__ pe,
                              const float* __restrict__ ce, const float* __restrict__ le,
                              float* __restrict__ h, int n) {
  int total = n * HD;
  int stride = gridDim.x * blockDim.x;
  for (int idx = blockIdx.x * blockDim.x + threadIdx.x; idx < total; idx += stride) {
    int node = idx >> 7, c = idx & (HD - 1);
    int lv = x[node * 3 + 0]; lv = lv < 0 ? 0 : (lv > 999 ? 999 : lv);
    int ct = x[node * 3 + 1]; ct = ct < 0 ? 0 : (ct > 4 ? 4 : ct);
    int th = x[node * 3 + 2]; th = th < 0 ? 0 : (th > 4999 ? 4999 : th);
    h[idx] = ce[ct * HD + c] + le[lv * HD + c] + pe[th * HD + c];
  }
}

// split 7 [128][128] f32 weight mats into bf16 hi/lo in WAVE-TILED fragment layout:
// out[((cg*4+k4)*64 + lane)*8 + j] = W[k][c], c = cg*16+(lane&15), k = (k4*4+(lane>>4))*8+j
__global__ void prep_w(const float* __restrict__ cW1, const float* __restrict__ cW2,
                       const float* __restrict__ gW1,
                       unsigned short* __restrict__ whi, unsigned short* __restrict__ wlo) {
  int m = blockIdx.x;
  const float* W = (m < 3) ? cW1 + (size_t)m * HD * HD
                 : (m < 6) ? cW2 + (size_t)(m - 3) * HD * HD : gW1;
  unsigned short* oh = whi + (size_t)m * HD * HD;
  unsigned short* ol = wlo + (size_t)m * HD * HD;
  for (int i = threadIdx.x; i < HD * HD; i += 256) {
    int j = i & 7;
    int l = (i >> 3) & 63;
    int p = i >> 9;            // cg*4 + k4
    int cg = p >> 2, k4 = p & 3;
    int c = cg * 16 + (l & 15);
    int k = (k4 * 4 + (l >> 4)) * 8 + j;
    float f = W[k * HD + c];
    unsigned short hh = f2bf(f);
    oh[i] = hh;
    ol[i] = f2bf(f - bf2f(hh));
  }
}

// ---------------- CSR build (XCD-owned dst windows, see R8) ---------------------

__global__ void hist_kernel(const int* __restrict__ ei, int* deg, int E, int Wwin) {
  int pass = blockIdx.x & 7;
  int b = blockIdx.x >> 3;
  int tstride = (gridDim.x >> 3) * blockDim.x;
  for (int e = b * blockDim.x + threadIdx.x; e < E; e += tstride) {
    int d = ei[E + e];
    if (d / Wwin == pass) atomicAdd(&deg[d], 1);
  }
}

#define SCAN_BS 1024
__global__ void scan1_kernel(const int* __restrict__ deg, int* __restrict__ off,
                             int* __restrict__ bsum, int n) {
  __shared__ int sh[256];
  int b = blockIdx.x, t = threadIdx.x;
  int base = b * SCAN_BS + t * 4;
  int v[4];
#pragma unroll
  for (int j = 0; j < 4; j++) v[j] = (base + j < n) ? deg[base + j] : 0;
  int s = v[0] + v[1] + v[2] + v[3];
  sh[t] = s;
  __syncthreads();
  for (int o = 1; o < 256; o <<= 1) {
    int x = (t >= o) ? sh[t - o] : 0;
    __syncthreads();
    sh[t] += x;
    __syncthreads();
  }
  int excl = sh[t] - s;
  if (t == 255) bsum[b] = sh[255];
  int run = excl;
#pragma unroll
  for (int j = 0; j < 4; j++) {
    if (base + j < n) off[base + j] = run;
    run += v[j];
  }
}

__global__ void scan2_kernel(int* bsum, int nb) {
  __shared__ int sh[128];
  int t = threadIdx.x;
  int v = (t < nb) ? bsum[t] : 0;
  sh[t] = v;
  __syncthreads();
  for (int o = 1; o < 128; o <<= 1) {
    int x = (t >= o) ? sh[t - o] : 0;
    __syncthreads();
    sh[t] += x;
    __syncthreads();
  }
  if (t < nb) bsum[t] = sh[t] - v;
}

__global__ void scan3_kernel(int* off, int* cursor, const int* __restrict__ bsum,
                             int n, int E) {
  int idx = blockIdx.x * blockDim.x + threadIdx.x;
  int stride = gridDim.x * blockDim.x;
  for (int i = idx; i < n; i += stride) {
    int v = off[i] + bsum[i >> 10];
    off[i] = v;
    cursor[i] = v;
  }
  if (idx == 0) off[n] = E;
}

__global__ void fill_kernel(const int* __restrict__ ei, int* cursor, int* csr_src,
                            int E, int Wwin) {
  int pass = blockIdx.x & 7;
  int b = blockIdx.x >> 3;
  int tstride = (gridDim.x >> 3) * blockDim.x;
  for (int e = b * blockDim.x + threadIdx.x; e < E; e += tstride) {
    int d = ei[E + e];
    if (d / Wwin == pass) {
      int pos = atomicAdd(&cursor[d], 1);
      csr_src[pos] = ei[e];
    }
  }
}

// ---------------- fused gather + split-bf16 MFMA GEMM (128-row tile, R9) -------
// Per 128-row block: agg_i = f(h[i]) + sum_e f(h[src_e]) gathered into LDS as bf16
// hi/lo; then z = agg @ W^T + bias via Ah*Bh + Ah*Bl + Al*Bh; fused column stats.
// Each wave covers FULL output rows (8 col-tiles) -> clean full-line writebacks.
template<bool BN, bool STATS>
__global__ __launch_bounds__(512, 4)
void gemm_gather(const float* __restrict__ h, const int* __restrict__ off,
                 const int* __restrict__ src, const float* __restrict__ ab,
                 const unsigned short* __restrict__ Whi,
                 const unsigned short* __restrict__ Wlo,
                 const float* __restrict__ bias, float* __restrict__ outf,
                 float* __restrict__ stat, int Nn) {
  __shared__ unsigned short XsH[128 * HD];
  __shared__ unsigned short XsL[128 * HD];
  __shared__ float red[2 * HD];
  int t = threadIdx.x;
  long rowbase = (long)blockIdx.x * 128;
  int grp = t >> 5, lane = t & 31;

  float4 a4, b4;
  if (BN) {
    a4 = *(const float4*)(ab + lane * 4);
    b4 = *(const float4*)(ab + HD + lane * 4);
  }
#define APPLY_BN(v) if (BN) { \
    v.x = fmaxf(v.x * a4.x + b4.x, 0.f); \
    v.y = fmaxf(v.y * a4.y + b4.y, 0.f); \
    v.z = fmaxf(v.z * a4.z + b4.z, 0.f); \
    v.w = fmaxf(v.w * a4.w + b4.w, 0.f); }

  // gather phase: 16 groups x 32 lanes; 8 rows/group; 8-deep edge unroll
  for (int rr = 0; rr < 8; rr++) {
    int r = grp + rr * 16;
    long row = rowbase + r; if (row > Nn - 1) row = Nn - 1;
    int s0 = off[row], s1 = off[row + 1];
    float4 acc0 = *(const float4*)(h + row * HD + lane * 4);
    APPLY_BN(acc0);
    float4 acc1 = {0.f, 0.f, 0.f, 0.f};
    float4 acc2 = {0.f, 0.f, 0.f, 0.f};
    float4 acc3 = {0.f, 0.f, 0.f, 0.f};
    int e = s0;
    for (; e + 8 <= s1; e += 8) {
      int i0 = src[e], i1 = src[e + 1], i2 = src[e + 2], i3 = src[e + 3];
      int i4 = src[e + 4], i5 = src[e + 5], i6 = src[e + 6], i7 = src[e + 7];
      float4 v0 = *(const float4*)(h + (size_t)i0 * HD + lane * 4);
      float4 v1 = *(const float4*)(h + (size_t)i1 * HD + lane * 4);
      float4 v2 = *(const float4*)(h + (size_t)i2 * HD + lane * 4);
      float4 v3 = *(const float4*)(h + (size_t)i3 * HD + lane * 4);
      float4 v4 = *(const float4*)(h + (size_t)i4 * HD + lane * 4);
      float4 v5 = *(const float4*)(h + (size_t)i5 * HD + lane * 4);
      float4 v6 = *(const float4*)(h + (size_t)i6 * HD + lane * 4);
      float4 v7 = *(const float4*)(h + (size_t)i7 * HD + lane * 4);
      APPLY_BN(v0); APPLY_BN(v1); APPLY_BN(v2); APPLY_BN(v3);
      APPLY_BN(v4); APPLY_BN(v5); APPLY_BN(v6); APPLY_BN(v7);
      acc0.x += v0.x + v4.x; acc0.y += v0.y + v4.y; acc0.z += v0.z + v4.z; acc0.w += v0.w + v4.w;
      acc1.x += v1.x + v5.x; acc1.y += v1.y + v5.y; acc1.z += v1.z + v5.z; acc1.w += v1.w + v5.w;
      acc2.x += v2.x + v6.x; acc2.y += v2.y + v6.y; acc2.z += v2.z + v6.z; acc2.w += v2.w + v6.w;
      acc3.x += v3.x + v7.x; acc3.y += v3.y + v7.y; acc3.z += v3.z + v7.z; acc3.w += v3.w + v7.w;
    }
    for (; e < s1; e++) {
      int s = src[e];
      float4 v = *(const float4*)(h + (size_t)s * HD + lane * 4);
      APPLY_BN(v);
      acc0.x += v.x; acc0.y += v.y; acc0.z += v.z; acc0.w += v.w;
    }
    acc0.x += acc1.x + acc2.x + acc3.x;
    acc0.y += acc1.y + acc2.y + acc3.y;
    acc0.z += acc1.z + acc2.z + acc3.z;
    acc0.w += acc1.w + acc2.w + acc3.w;
    float f[4] = {acc0.x, acc0.y, acc0.z, acc0.w};
    us4 hi, lo;
#pragma unroll
    for (int j = 0; j < 4; j++) {
      unsigned short hh = f2bf(f[j]);
      hi[j] = hh;
      lo[j] = f2bf(f[j] - bf2f(hh));
    }
    int g8 = lane >> 1;
    int offl = r * HD + (((g8 ^ (r & 7)) << 3)) + (lane & 1) * 4;
    *(us4*)(XsH + offl) = hi;
    *(us4*)(XsL + offl) = lo;
  }
#undef APPLY_BN
  if (STATS && t < 2 * HD) red[t] = 0.f;
  __syncthreads();

  int w = t >> 6, l = t & 63;
  int lr = l & 15, lg = l >> 4;

  f32x4 acc[8];
#pragma unroll
  for (int ct = 0; ct < 8; ct++) acc[ct] = (f32x4){0.f, 0.f, 0.f, 0.f};

  bf16x8 aH[4], aL[4];
  int arow = w * 16 + lr;
#pragma unroll
  for (int k4 = 0; k4 < 4; k4++) {
    int kg = k4 * 4 + lg;
    int offa = arow * HD + (((kg ^ (arow & 7)) << 3));
    aH[k4] = *(bf16x8*)(XsH + offa);
    aL[k4] = *(bf16x8*)(XsL + offa);
  }
#pragma unroll
  for (int ct = 0; ct < 8; ct++) {
#pragma unroll
    for (int k4 = 0; k4 < 4; k4++) {
      int bo = (((ct << 2) + k4) * 64 + l) * 8;
      bf16x8 bH = *(const bf16x8*)(Whi + bo);
      bf16x8 bL = *(const bf16x8*)(Wlo + bo);
      acc[ct] = __builtin_amdgcn_mfma_f32_16x16x32_bf16(aH[k4], bH, acc[ct], 0, 0, 0);
      acc[ct] = __builtin_amdgcn_mfma_f32_16x16x32_bf16(aH[k4], bL, acc[ct], 0, 0, 0);
      acc[ct] = __builtin_amdgcn_mfma_f32_16x16x32_bf16(aL[k4], bH, acc[ct], 0, 0, 0);
    }
  }

  float s[8], ss[8];
#pragma unroll
  for (int ct = 0; ct < 8; ct++) { s[ct] = 0.f; ss[ct] = 0.f; }
#pragma unroll
  for (int jj = 0; jj < 4; jj++) {
    long row = rowbase + w * 16 + lg * 4 + jj;
    bool ok = row < Nn;
#pragma unroll
    for (int ct = 0; ct < 8; ct++) {
      float v = acc[ct][jj] + bias[ct * 16 + lr];
      if (ok) {
        outf[row * HD + ct * 16 + lr] = v;
        if (STATS) { s[ct] += v; ss[ct] += v * v; }
      }
    }
  }
  if (STATS) {
#pragma unroll
    for (int ct = 0; ct < 8; ct++) {
      float sv = s[ct], sq = ss[ct];
      sv += __shfl_xor(sv, 16); sq += __shfl_xor(sq, 16);
      sv += __shfl_xor(sv, 32); sq += __shfl_xor(sq, 32);
      if (lg == 0) {
        atomicAdd(&red[ct * 16 + lr], sv);
        atomicAdd(&red[HD + ct * 16 + lr], sq);
      }
    }
    __syncthreads();
    float* st = stat + (blockIdx.x & 3) * 256;
    if (t < 2 * HD) atomicAdd(&st[t], red[t]);
  }
}

// ---------------- split-bf16 MFMA GEMM (contiguous, 64-row tile, 4 waves) ------
// Each wave = 16 rows x FULL 128 cols (8 col-tiles) -> clean full-line writes.
// 33 KB LDS -> 4 blocks/CU (16 waves/CU) for streaming overlap.
template<bool INBN, bool GATE, bool STATS>
__global__ __launch_bounds__(256, 4)
void gemm_split(const float* __restrict__ X, const unsigned short* __restrict__ Whi,
                const unsigned short* __restrict__ Wlo,
                const float* __restrict__ bias, const float* __restrict__ ab,
                const float* __restrict__ w2, float* __restrict__ outf,
                float* __restrict__ gate, float* __restrict__ stat, int Nn) {
  __shared__ unsigned short XsH[64 * HD];
  __shared__ unsigned short XsL[64 * HD];
  __shared__ float red[2 * HD];
  int t = threadIdx.x;
  long rowbase = (long)blockIdx.x * 64;

#pragma unroll
  for (int it = 0; it < 8; it++) {
    int i = (t + it * 256) * 4;
    int r = i >> 7, k = i & (HD - 1);
    long row = rowbase + r; if (row > Nn - 1) row = Nn - 1;
    float4 v = *(const float4*)(X + row * HD + k);
    float f[4] = {v.x, v.y, v.z, v.w};
    if (INBN) {
#pragma unroll
      for (int j = 0; j < 4; j++)
        f[j] = fmaxf(f[j] * ab[k + j] + ab[HD + k + j], 0.f);
    }
    us4 hi, lo;
#pragma unroll
    for (int j = 0; j < 4; j++) {
      unsigned short hh = f2bf(f[j]);
      hi[j] = hh;
      lo[j] = f2bf(f[j] - bf2f(hh));
    }
    int g = k >> 3;
    int off = r * HD + ((((g ^ (r & 7)) << 3)) | (k & 7));
    *(us4*)(XsH + off) = hi;
    *(us4*)(XsL + off) = lo;
  }
  if (STATS) red[t] = 0.f;   // 256 threads cover 2*HD
  __syncthreads();

  int w = t >> 6, l = t & 63;
  int lr = l & 15, lg = l >> 4;

  f32x4 acc[8];
#pragma unroll
  for (int ct = 0; ct < 8; ct++) acc[ct] = (f32x4){0.f, 0.f, 0.f, 0.f};

  bf16x8 aH[4], aL[4];
  int arow = w * 16 + lr;
#pragma unroll
  for (int k4 = 0; k4 < 4; k4++) {
    int kg = k4 * 4 + lg;
    int off = arow * HD + (((kg ^ (arow & 7)) << 3));
    aH[k4] = *(bf16x8*)(XsH + off);
    aL[k4] = *(bf16x8*)(XsL + off);
  }
#pragma unroll
  for (int ct = 0; ct < 8; ct++) {
#pragma unroll
    for (int k4 = 0; k4 < 4; k4++) {
      int bo = (((ct << 2) + k4) * 64 + l) * 8;
      bf16x8 bH = *(const bf16x8*)(Whi + bo);
      bf16x8 bL = *(const bf16x8*)(Wlo + bo);
      acc[ct] = __builtin_amdgcn_mfma_f32_16x16x32_bf16(aH[k4], bH, acc[ct], 0, 0, 0);
      acc[ct] = __builtin_amdgcn_mfma_f32_16x16x32_bf16(aH[k4], bL, acc[ct], 0, 0, 0);
      acc[ct] = __builtin_amdgcn_mfma_f32_16x16x32_bf16(aL[k4], bH, acc[ct], 0, 0, 0);
    }
  }

  if (GATE) {
#pragma unroll
    for (int jj = 0; jj < 4; jj++) {
      float p = 0.f;
#pragma unroll
      for (int ct = 0; ct < 8; ct++) {
        float v = fmaxf(acc[ct][jj] + bias[ct * 16 + lr], 0.f);
        p += v * w2[ct * 16 + lr];
      }
      p += __shfl_xor(p, 1);
      p += __shfl_xor(p, 2);
      p += __shfl_xor(p, 4);
      p += __shfl_xor(p, 8);
      long row = rowbase + w * 16 + lg * 4 + jj;
      if (lr == 0 && row < Nn) gate[row] = p;
    }
  } else {
    float s[8], ss[8];
#pragma unroll
    for (int ct = 0; ct < 8; ct++) { s[ct] = 0.f; ss[ct] = 0.f; }
#pragma unroll
    for (int jj = 0; jj < 4; jj++) {
      long row = rowbase + w * 16 + lg * 4 + jj;
      bool ok = row < Nn;
#pragma unroll
      for (int ct = 0; ct < 8; ct++) {
        float v = acc[ct][jj] + bias[ct * 16 + lr];
        if (ok) {
          outf[row * HD + ct * 16 + lr] = v;
          if (STATS) { s[ct] += v; ss[ct] += v * v; }
        }
      }
    }
    if (STATS) {
#pragma unroll
      for (int ct = 0; ct < 8; ct++) {
        float sv = s[ct], sq = ss[ct];
        sv += __shfl_xor(sv, 16); sq += __shfl_xor(sq, 16);
        sv += __shfl_xor(sv, 32); sq += __shfl_xor(sq, 32);
        if (lg == 0) {
          atomicAdd(&red[ct * 16 + lr], sv);
          atomicAdd(&red[HD + ct * 16 + lr], sq);
        }
      }
      __syncthreads();
      float* st = stat + (blockIdx.x & 3) * 256;
      atomicAdd(&st[t], red[t]);   // 256 threads cover 2*HD
    }
  }
}

__global__ void finalize_kernel(const float* __restrict__ stat, const float* __restrict__ g,
                                const float* __restrict__ be, float* ab, float inv_n) {
  int c = threadIdx.x;
  float s = stat[c] + stat[256 + c] + stat[512 + c] + stat[768 + c];
  float sq = stat[HD + c] + stat[256 + HD + c] + stat[512 + HD + c] + stat[768 + HD + c];
  float mean = s * inv_n;
  float var = sq * inv_n - mean * mean;
  float inv = rsqrtf(var + 1e-5f);
  float a = inv * g[c];
  ab[c] = a;
  ab[HD + c] = be[c] - mean * a;
}

__global__ void finalize1_kernel(const float* __restrict__ stat, const float* __restrict__ g,
                                 const float* __restrict__ be, float* ab, float inv_n) {
  int c = threadIdx.x;
  float mean = stat[c] * inv_n;
  float var = stat[HD + c] * inv_n - mean * mean;
  float inv = rsqrtf(var + 1e-5f);
  float a = inv * g[c];
  ab[c] = a;
  ab[HD + c] = be[c] - mean * a;
}

__global__ void bound_kernel(const int* __restrict__ batch, int* gs, int N, int G) {
  int i = blockIdx.x * blockDim.x + threadIdx.x;
  if (i >= N) return;
  int b = batch[i];
  int prev = (i == 0) ? -1 : batch[i - 1];
  for (int g = prev + 1; g <= b; g++) gs[g] = i;
  if (i == N - 1)
    for (int g = b + 1; g <= G; g++) gs[g] = N;
}

__global__ void fused_pool(const float* __restrict__ h, const float* __restrict__ gate,
                           const int* __restrict__ gs, const float* __restrict__ ab,
                           float* __restrict__ pooled) {
  int g = blockIdx.x;
  int t = threadIdx.x;
  int s0 = gs[g], s1 = gs[g + 1];
  if (s0 >= s1) { pooled[(size_t)g * HD + t] = 0.f; return; }
  __shared__ float red[HD];
  float m = -INFINITY;
  for (int i = s0 + t; i < s1; i += HD) m = fmaxf(m, gate[i]);
  red[t] = m;
  __syncthreads();
  for (int o = 64; o > 0; o >>= 1) {
    if (t < o) red[t] = fmaxf(red[t], red[t + o]);
    __syncthreads();
  }
  m = red[0];
  __syncthreads();
  float s = 0.f;
  for (int i = s0 + t; i < s1; i += HD) s += expf(gate[i] - m);
  red[t] = s;
  __syncthreads();
  for (int o = 64; o > 0; o >>= 1) {
    if (t < o) red[t] += red[t + o];
    __syncthreads();
  }
  float inv = 1.f / red[0];
  float a = ab[t], b = ab[HD + t];
  float acc = 0.f;
  int i = s0;
  for (; i + 4 <= s1; i += 4) {
    float al0 = expf(gate[i] - m);
    float al1 = expf(gate[i + 1] - m);
    float al2 = expf(gate[i + 2] - m);
    float al3 = expf(gate[i + 3] - m);
    float v0 = fmaxf(h[(size_t)(i + 0) * HD + t] * a + b, 0.f);
    float v1 = fmaxf(h[(size_t)(i + 1) * HD + t] * a + b, 0.f);
    float v2 = fmaxf(h[(size_t)(i + 2) * HD + t] * a + b, 0.f);
    float v3 = fmaxf(h[(size_t)(i + 3) * HD + t] * a + b, 0.f);
    acc += al0 * v0 + al1 * v1 + al2 * v2 + al3 * v3;
  }
  for (; i < s1; i++) {
    float al = expf(gate[i] - m);
    float v = fmaxf(h[(size_t)i * HD + t] * a + b, 0.f);
    acc += al * v;
  }
  pooled[(size_t)g * HD + t] = acc * inv;
}

// f32 classifier GEMM: zc[G x 128] = pooled @ W + bias
__global__ __launch_bounds__(256, 4)
void gemm_f32(const float* __restrict__ X, const float* __restrict__ W,
              const float* __restrict__ bias, float* __restrict__ out, int Nn) {
  __shared__ float XsT[32][132];
  __shared__ float Ws[32][HD];
  int t = threadIdx.x;
  int r0 = (t >> 4) * 8;
  int c0 = (t & 15) * 8;
  long rowbase = (long)blockIdx.x * 128;

  float acc[8][8];
#pragma unroll
  for (int ci = 0; ci < 8; ci++) {
    float bv = bias[c0 + ci];
#pragma unroll
    for (int ri = 0; ri < 8; ri++) acc[ri][ci] = bv;
  }

  int sr = t >> 1;
  int hf = t & 1;
  long srow = rowbase + sr; if (srow > Nn - 1) srow = Nn - 1;
  const float* xrow = X + srow * HD;

  for (int k0 = 0; k0 < HD; k0 += 32) {
    __syncthreads();
#pragma unroll
    for (int j = 0; j < 4; j++) {
      int i = j * 1024 + t * 4;
      int kk = i >> 7, c = i & (HD - 1);
      *(float4*)&Ws[kk][c] = *(const float4*)&W[(size_t)(k0 + kk) * HD + c];
    }
#pragma unroll
    for (int j = 0; j < 4; j++) {
      int kc = k0 + hf * 16 + j * 4;
      float4 v = *(const float4*)&xrow[kc];
      int kl = hf * 16 + j * 4;
      XsT[kl + 0][sr] = v.x;
      XsT[kl + 1][sr] = v.y;
      XsT[kl + 2][sr] = v.z;
      XsT[kl + 3][sr] = v.w;
    }
    __syncthreads();
#pragma unroll 8
    for (int kk = 0; kk < 32; kk++) {
      float4 a0 = *(float4*)&XsT[kk][r0];
      float4 a1 = *(float4*)&XsT[kk][r0 + 4];
      float4 b0 = *(float4*)&Ws[kk][c0];
      float4 b1 = *(float4*)&Ws[kk][c0 + 4];
      float ar[8] = {a0.x, a0.y, a0.z, a0.w, a1.x, a1.y, a1.z, a1.w};
      float bc[8] = {b0.x, b0.y, b0.z, b0.w, b1.x, b1.y, b1.z, b1.w};
#pragma unroll
      for (int ri = 0; ri < 8; ri++)
#pragma unroll
        for (int ci = 0; ci < 8; ci++) acc[ri][ci] += ar[ri] * bc[ci];
    }
  }

#pragma unroll
  for (int ri = 0; ri < 8; ri++) {
    long row = rowbase + r0 + ri;
    if (row < Nn) {
      float4 o0 = {acc[ri][0], acc[ri][1], acc[ri][2], acc[ri][3]};
      float4 o1 = {acc[ri][4], acc[ri][5], acc[ri][6], acc[ri][7]};
      *(float4*)&out[row * HD + c0] = o0;
      *(float4*)&out[row * HD + c0 + 4] = o1;
    }
  }
}

__global__ void stats_f32(const float* __restrict__ z, float* stat, int n) {
  int c = threadIdx.x & (HD - 1);
  int rg = threadIdx.x >> 7;
  float s = 0.f, ss = 0.f;
  for (int r = blockIdx.x * 2 + rg; r < n; r += gridDim.x * 2) {
    float v = z[(size_t)r * HD + c];
    s += v; ss += v * v;
  }
  __shared__ float S[2][HD], SS[2][HD];
  S[rg][c] = s; SS[rg][c] = ss;
  __syncthreads();
  if (threadIdx.x < HD) {
    atomicAdd(&stat[c], S[0][c] + S[1][c]);
    atomicAdd(&stat[HD + c], SS[0][c] + SS[1][c]);
  }
}

__global__ void cls_out_kernel(const float* __restrict__ zc, const float* __restrict__ ab,
                               const float* __restrict__ W2, const float* __restrict__ b2,
                               float* out, int G) {
  int row = blockIdx.x;
  int t = threadIdx.x;
  float v0 = fmaxf(zc[(size_t)row * HD + t] * ab[t] + ab[HD + t], 0.f);
  float v1 = fmaxf(zc[(size_t)row * HD + 64 + t] * ab[64 + t] + ab[HD + 64 + t], 0.f);
  for (int o = 0; o < 10; o++) {
    float p = v0 * W2[t * 10 + o] + v1 * W2[(64 + t) * 10 + o];
#pragma unroll
    for (int s = 32; s > 0; s >>= 1) p += __shfl_down(p, s);
    if (t == 0) out[row * 10 + o] = p + b2[o];
  }
}

extern "C" void kernel_launch(void* const* d_in, const int* in_sizes, int n_in,
                              void* d_out, int out_size, void* d_ws, size_t ws_size,
                              hipStream_t stream) {
  const int* x     = (const int*)d_in[0];
  const int* ei    = (const int*)d_in[1];
  const int* batch = (const int*)d_in[2];
  const float* pe  = (const float*)d_in[4];
  const float* ce  = (const float*)d_in[5];
  const float* le  = (const float*)d_in[6];
  const float* cW1 = (const float*)d_in[7];
  const float* cb1 = (const float*)d_in[8];
  const float* cg1 = (const float*)d_in[9];
  const float* cbe1= (const float*)d_in[10];
  const float* cW2 = (const float*)d_in[11];
  const float* cb2 = (const float*)d_in[12];
  const float* ngm = (const float*)d_in[13];
  const float* nbe = (const float*)d_in[14];
  const float* gW1 = (const float*)d_in[15];
  const float* gb1 = (const float*)d_in[16];
  const float* gW2 = (const float*)d_in[17];
  const float* clW1= (const float*)d_in[19];
  const float* clb1= (const float*)d_in[20];
  const float* clg = (const float*)d_in[21];
  const float* clbe= (const float*)d_in[22];
  const float* clW2= (const float*)d_in[23];
  const float* clb2= (const float*)d_in[24];

  int N = in_sizes[2];
  int E = in_sizes[1] / 2;
  int G = out_size / 10;

  float* buf0   = (float*)d_ws;              // h (f32)
  float* buf1   = buf0 + (size_t)N * HD;     // z (f32)
  float* pooled = buf1 + (size_t)N * HD;     // G x 128
  float* gate   = pooled + (size_t)G * HD;   // N
  float* zc     = gate + N;                  // G x 128
  float* stats  = zc + (size_t)G * HD;       // 7 x 1024
  float* ab     = stats + 7 * 1024;          // 7 x 256
  unsigned short* whi = (unsigned short*)(ab + 7 * 256);  // 7 x 128 x 128 bf16
  unsigned short* wlo = whi + 7 * HD * HD;
  int* csr_off  = (int*)(wlo + 7 * HD * HD); // N+1
  int* cursor   = csr_off + (N + 1);         // N
  int* bsum     = cursor + N;                // 128
  int* gs       = bsum + 128;                // G+1
  int* csr_src  = gs + (G + 1);              // E

  float* out = (float*)d_out;
  int gatherBlocks = (N + 127) / 128;
  int splitBlocks  = (N + 63) / 64;
  int Wwin = (N + 7) / 8;

  zero_f<<<28, 256, 0, stream>>>(stats, 7 * 1024);
  encode_kernel<<<2048, 256, 0, stream>>>(x, pe, ce, le, buf0, N);
  prep_w<<<7, 256, 0, stream>>>(cW1, cW2, gW1, whi, wlo);

  // CSR build (XCD-owned dst windows; reused by all 3 layers)
  int nb = (N + SCAN_BS - 1) / SCAN_BS;
  zero_int<<<256, 256, 0, stream>>>(cursor, N);
  hist_kernel<<<2048, 256, 0, stream>>>(ei, cursor, E, Wwin);
  scan1_kernel<<<nb, 256, 0, stream>>>(cursor, csr_off, bsum, N);
  scan2_kernel<<<1, 128, 0, stream>>>(bsum, nb);
  scan3_kernel<<<256, 256, 0, stream>>>(csr_off, cursor, bsum, N, E);
  fill_kernel<<<2048, 256, 0, stream>>>(ei, cursor, csr_src, E, Wwin);
  bound_kernel<<<(N + 255) / 256, 256, 0, stream>>>(batch, gs, N, G);

  for (int l = 0; l < 3; l++) {
    float* abPrev = ab + (l - 1) * 512 + 256;
    if (l == 0)
      gemm_gather<false, true><<<gatherBlocks, 512, 0, stream>>>(
          buf0, csr_off, csr_src, nullptr,
          whi + (size_t)l * HD * HD, wlo + (size_t)l * HD * HD,
          cb1 + l * HD, buf1, stats + l * 2048, N);
    else
      gemm_gather<true, true><<<gatherBlocks, 512, 0, stream>>>(
          buf0, csr_off, csr_src, abPrev,
          whi + (size_t)l * HD * HD, wlo + (size_t)l * HD * HD,
          cb1 + l * HD, buf1, stats + l * 2048, N);
    finalize_kernel<<<1, 128, 0, stream>>>(stats + l * 2048, cg1 + l * HD, cbe1 + l * HD,
                                           ab + l * 512, 1.f / N);
    gemm_split<true, false, true><<<splitBlocks, 256, 0, stream>>>(
        buf1, whi + (size_t)(3 + l) * HD * HD, wlo + (size_t)(3 + l) * HD * HD,
        cb2 + l * HD, ab + l * 512, nullptr, buf0, nullptr, stats + l * 2048 + 1024, N);
    finalize_kernel<<<1, 128, 0, stream>>>(stats + l * 2048 + 1024, ngm + l * HD, nbe + l * HD,
                                           ab + l * 512 + 256, 1.f / N);
  }

  const float* abFin = ab + 2 * 512 + 256;
  gemm_split<true, true, false><<<splitBlocks, 256, 0, stream>>>(
      buf0, whi + (size_t)6 * HD * HD, wlo + (size_t)6 * HD * HD,
      gb1, abFin, gW2, nullptr, gate, nullptr, N);
  fused_pool<<<G, HD, 0, stream>>>(buf0, gate, gs, abFin, pooled);

  // classifier tail in f32
  gemm_f32<<<(G + 127) / 128, 256, 0, stream>>>(pooled, clW1, clb1, zc, G);
  stats_f32<<<64, 256, 0, stream>>>(zc, stats + 6 * 1024, G);
  finalize1_kernel<<<1, 128, 0, stream>>>(stats + 6 * 1024, clg, clbe, ab + 6 * 256, 1.f / G);
  cls_out_kernel<<<G, 64, 0, stream>>>(zc, ab + 6 * 256, clW2, clb2, out, G);
}

// Round 12
// 857.753 us; speedup vs baseline: 1.0806x; 1.0347x over previous
//
#include <hip/hip_runtime.h>
#include <math.h>

#define HD 128

typedef __attribute__((ext_vector_type(8))) short bf16x8;
typedef __attribute__((ext_vector_type(8))) unsigned short us8;
typedef __attribute__((ext_vector_type(4))) unsigned short us4;
typedef __attribute__((ext_vector_type(4))) float f32x4;

__device__ __forceinline__ float bf2f(unsigned short u) {
  union { unsigned int i; float f; } v; v.i = ((unsigned int)u) << 16; return v.f;
}
__device__ __forceinline__ unsigned short f2bf(float f) {
  union { float f; unsigned int i; } v; v.f = f;
  unsigned int u = v.i;
  u += 0x7FFFu + ((u >> 16) & 1u);
  return (unsigned short)(u >> 16);
}

__global__ void zero_f(float* p, int n) {
  int i = blockIdx.x * blockDim.x + threadIdx.x;
  if (i < n) p[i] = 0.f;
}

__global__ void zero_int(int* p, int n) {
  int stride = gridDim.x * blockDim.x;
  for (int i = blockIdx.x * blockDim.x + threadIdx.x; i < n; i += stride) p[i] = 0;
}

__global__ void encode_kernel(const int* __restrict__ x, const float* __restrict__ pe,
                              const float* __restrict__ ce, const float* __restrict__ le,
                              float* __restrict__ h, int n) {
  int total = n * HD;
  int stride = gridDim.x * blockDim.x;
  for (int idx = blockIdx.x * blockDim.x + threadIdx.x; idx < total; idx += stride) {
    int node = idx >> 7, c = idx & (HD - 1);
    int lv = x[node * 3 + 0]; lv = lv < 0 ? 0 : (lv > 999 ? 999 : lv);
    int ct = x[node * 3 + 1]; ct = ct < 0 ? 0 : (ct > 4 ? 4 : ct);
    int th = x[node * 3 + 2]; th = th < 0 ? 0 : (th > 4999 ? 4999 : th);
    h[idx] = ce[ct * HD + c] + le[lv * HD + c] + pe[th * HD + c];
  }
}

// split 7 [128][128] f32 weight mats into bf16 hi/lo in WAVE-TILED fragment layout:
// out[((cg*4+k4)*64 + lane)*8 + j] = W[k][c], c = cg*16+(lane&15), k = (k4*4+(lane>>4))*8+j
__global__ void prep_w(const float* __restrict__ cW1, const float* __restrict__ cW2,
                       const float* __restrict__ gW1,
                       unsigned short* __restrict__ whi, unsigned short* __restrict__ wlo) {
  int m = blockIdx.x;
  const float* W = (m < 3) ? cW1 + (size_t)m * HD * HD
                 : (m < 6) ? cW2 + (size_t)(m - 3) * HD * HD : gW1;
  unsigned short* oh = whi + (size_t)m * HD * HD;
  unsigned short* ol = wlo + (size_t)m * HD * HD;
  for (int i = threadIdx.x; i < HD * HD; i += 256) {
    int j = i & 7;
    int l = (i >> 3) & 63;
    int p = i >> 9;            // cg*4 + k4
    int cg = p >> 2, k4 = p & 3;
    int c = cg * 16 + (l & 15);
    int k = (k4 * 4 + (l >> 4)) * 8 + j;
    float f = W[k * HD + c];
    unsigned short hh = f2bf(f);
    oh[i] = hh;
    ol[i] = f2bf(f - bf2f(hh));
  }
}

// ---------------- CSR build (XCD-owned dst windows, see R8) ---------------------

__global__ void hist_kernel(const int* __restrict__ ei, int* deg, int E, int Wwin) {
  int pass = blockIdx.x & 7;
  int b = blockIdx.x >> 3;
  int tstride = (gridDim.x >> 3) * blockDim.x;
  for (int e = b * blockDim.x + threadIdx.x; e < E; e += tstride) {
    int d = ei[E + e];
    if (d / Wwin == pass) atomicAdd(&deg[d], 1);
  }
}

#define SCAN_BS 1024
__global__ void scan1_kernel(const int* __restrict__ deg, int* __restrict__ off,
                             int* __restrict__ bsum, int n) {
  __shared__ int sh[256];
  int b = blockIdx.x, t = threadIdx.x;
  int base = b * SCAN_BS + t * 4;
  int v[4];
#pragma unroll
  for (int j = 0; j < 4; j++) v[j] = (base + j < n) ? deg[base + j] : 0;
  int s = v[0] + v[1] + v[2] + v[3];
  sh[t] = s;
  __syncthreads();
  for (int o = 1; o < 256; o <<= 1) {
    int x = (t >= o) ? sh[t - o] : 0;
    __syncthreads();
    sh[t] += x;
    __syncthreads();
  }
  int excl = sh[t] - s;
  if (t == 255) bsum[b] = sh[255];
  int run = excl;
#pragma unroll
  for (int j = 0; j < 4; j++) {
    if (base + j < n) off[base + j] = run;
    run += v[j];
  }
}

__global__ void scan2_kernel(int* bsum, int nb) {
  __shared__ int sh[128];
  int t = threadIdx.x;
  int v = (t < nb) ? bsum[t] : 0;
  sh[t] = v;
  __syncthreads();
  for (int o = 1; o < 128; o <<= 1) {
    int x = (t >= o) ? sh[t - o] : 0;
    __syncthreads();
    sh[t] += x;
    __syncthreads();
  }
  if (t < nb) bsum[t] = sh[t] - v;
}

__global__ void scan3_kernel(int* off, int* cursor, const int* __restrict__ bsum,
                             int n, int E) {
  int idx = blockIdx.x * blockDim.x + threadIdx.x;
  int stride = gridDim.x * blockDim.x;
  for (int i = idx; i < n; i += stride) {
    int v = off[i] + bsum[i >> 10];
    off[i] = v;
    cursor[i] = v;
  }
  if (idx == 0) off[n] = E;
}

__global__ void fill_kernel(const int* __restrict__ ei, int* cursor, int* csr_src,
                            int E, int Wwin) {
  int pass = blockIdx.x & 7;
  int b = blockIdx.x >> 3;
  int tstride = (gridDim.x >> 3) * blockDim.x;
  for (int e = b * blockDim.x + threadIdx.x; e < E; e += tstride) {
    int d = ei[E + e];
    if (d / Wwin == pass) {
      int pos = atomicAdd(&cursor[d], 1);
      csr_src[pos] = ei[e];
    }
  }
}

// ---------------- fused gather + split-bf16 MFMA GEMM (128-row tile) -----------
// Per 128-row block: agg_i = f(h[i]) + sum_e f(h[src_e]) gathered into LDS as bf16
// hi/lo; then z = agg @ W^T + bias via Ah*Bh + Ah*Bl + Al*Bh; fused column stats.
// Each wave covers FULL output rows (8 col-tiles) -> clean full-line writebacks.
template<bool BN, bool STATS>
__global__ __launch_bounds__(512, 4)
void gemm_gather(const float* __restrict__ h, const int* __restrict__ off,
                 const int* __restrict__ src, const float* __restrict__ ab,
                 const unsigned short* __restrict__ Whi,
                 const unsigned short* __restrict__ Wlo,
                 const float* __restrict__ bias, float* __restrict__ outf,
                 float* __restrict__ stat, int Nn) {
  __shared__ unsigned short XsH[128 * HD];
  __shared__ unsigned short XsL[128 * HD];
  __shared__ float red[2 * HD];
  int t = threadIdx.x;
  long rowbase = (long)blockIdx.x * 128;
  int grp = t >> 5, lane = t & 31;

  float4 a4, b4;
  if (BN) {
    a4 = *(const float4*)(ab + lane * 4);
    b4 = *(const float4*)(ab + HD + lane * 4);
  }
#define APPLY_BN(v) if (BN) { \
    v.x = fmaxf(v.x * a4.x + b4.x, 0.f); \
    v.y = fmaxf(v.y * a4.y + b4.y, 0.f); \
    v.z = fmaxf(v.z * a4.z + b4.z, 0.f); \
    v.w = fmaxf(v.w * a4.w + b4.w, 0.f); }

  // gather phase: 16 groups x 32 lanes; 8 rows/group; 8-deep edge unroll
  for (int rr = 0; rr < 8; rr++) {
    int r = grp + rr * 16;
    long row = rowbase + r; if (row > Nn - 1) row = Nn - 1;
    int s0 = off[row], s1 = off[row + 1];
    float4 acc0 = *(const float4*)(h + row * HD + lane * 4);
    APPLY_BN(acc0);
    float4 acc1 = {0.f, 0.f, 0.f, 0.f};
    float4 acc2 = {0.f, 0.f, 0.f, 0.f};
    float4 acc3 = {0.f, 0.f, 0.f, 0.f};
    int e = s0;
    for (; e + 8 <= s1; e += 8) {
      int i0 = src[e], i1 = src[e + 1], i2 = src[e + 2], i3 = src[e + 3];
      int i4 = src[e + 4], i5 = src[e + 5], i6 = src[e + 6], i7 = src[e + 7];
      float4 v0 = *(const float4*)(h + (size_t)i0 * HD + lane * 4);
      float4 v1 = *(const float4*)(h + (size_t)i1 * HD + lane * 4);
      float4 v2 = *(const float4*)(h + (size_t)i2 * HD + lane * 4);
      float4 v3 = *(const float4*)(h + (size_t)i3 * HD + lane * 4);
      float4 v4 = *(const float4*)(h + (size_t)i4 * HD + lane * 4);
      float4 v5 = *(const float4*)(h + (size_t)i5 * HD + lane * 4);
      float4 v6 = *(const float4*)(h + (size_t)i6 * HD + lane * 4);
      float4 v7 = *(const float4*)(h + (size_t)i7 * HD + lane * 4);
      APPLY_BN(v0); APPLY_BN(v1); APPLY_BN(v2); APPLY_BN(v3);
      APPLY_BN(v4); APPLY_BN(v5); APPLY_BN(v6); APPLY_BN(v7);
      acc0.x += v0.x + v4.x; acc0.y += v0.y + v4.y; acc0.z += v0.z + v4.z; acc0.w += v0.w + v4.w;
      acc1.x += v1.x + v5.x; acc1.y += v1.y + v5.y; acc1.z += v1.z + v5.z; acc1.w += v1.w + v5.w;
      acc2.x += v2.x + v6.x; acc2.y += v2.y + v6.y; acc2.z += v2.z + v6.z; acc2.w += v2.w + v6.w;
      acc3.x += v3.x + v7.x; acc3.y += v3.y + v7.y; acc3.z += v3.z + v7.z; acc3.w += v3.w + v7.w;
    }
    for (; e < s1; e++) {
      int s = src[e];
      float4 v = *(const float4*)(h + (size_t)s * HD + lane * 4);
      APPLY_BN(v);
      acc0.x += v.x; acc0.y += v.y; acc0.z += v.z; acc0.w += v.w;
    }
    acc0.x += acc1.x + acc2.x + acc3.x;
    acc0.y += acc1.y + acc2.y + acc3.y;
    acc0.z += acc1.z + acc2.z + acc3.z;
    acc0.w += acc1.w + acc2.w + acc3.w;
    float f[4] = {acc0.x, acc0.y, acc0.z, acc0.w};
    us4 hi, lo;
#pragma unroll
    for (int j = 0; j < 4; j++) {
      unsigned short hh = f2bf(f[j]);
      hi[j] = hh;
      lo[j] = f2bf(f[j] - bf2f(hh));
    }
    int g8 = lane >> 1;
    int offl = r * HD + (((g8 ^ (r & 7)) << 3)) + (lane & 1) * 4;
    *(us4*)(XsH + offl) = hi;
    *(us4*)(XsL + offl) = lo;
  }
#undef APPLY_BN
  if (STATS && t < 2 * HD) red[t] = 0.f;
  __syncthreads();

  int w = t >> 6, l = t & 63;
  int lr = l & 15, lg = l >> 4;

  f32x4 acc[8];
#pragma unroll
  for (int ct = 0; ct < 8; ct++) acc[ct] = (f32x4){0.f, 0.f, 0.f, 0.f};

  bf16x8 aH[4], aL[4];
  int arow = w * 16 + lr;
#pragma unroll
  for (int k4 = 0; k4 < 4; k4++) {
    int kg = k4 * 4 + lg;
    int offa = arow * HD + (((kg ^ (arow & 7)) << 3));
    aH[k4] = *(bf16x8*)(XsH + offa);
    aL[k4] = *(bf16x8*)(XsL + offa);
  }
#pragma unroll
  for (int ct = 0; ct < 8; ct++) {
#pragma unroll
    for (int k4 = 0; k4 < 4; k4++) {
      int bo = (((ct << 2) + k4) * 64 + l) * 8;
      bf16x8 bH = *(const bf16x8*)(Whi + bo);
      bf16x8 bL = *(const bf16x8*)(Wlo + bo);
      acc[ct] = __builtin_amdgcn_mfma_f32_16x16x32_bf16(aH[k4], bH, acc[ct], 0, 0, 0);
      acc[ct] = __builtin_amdgcn_mfma_f32_16x16x32_bf16(aH[k4], bL, acc[ct], 0, 0, 0);
      acc[ct] = __builtin_amdgcn_mfma_f32_16x16x32_bf16(aL[k4], bH, acc[ct], 0, 0, 0);
    }
  }

  float s[8], ss[8];
#pragma unroll
  for (int ct = 0; ct < 8; ct++) { s[ct] = 0.f; ss[ct] = 0.f; }
#pragma unroll
  for (int jj = 0; jj < 4; jj++) {
    long row = rowbase + w * 16 + lg * 4 + jj;
    bool ok = row < Nn;
#pragma unroll
    for (int ct = 0; ct < 8; ct++) {
      float v = acc[ct][jj] + bias[ct * 16 + lr];
      if (ok) {
        outf[row * HD + ct * 16 + lr] = v;
        if (STATS) { s[ct] += v; ss[ct] += v * v; }
      }
    }
  }
  if (STATS) {
#pragma unroll
    for (int ct = 0; ct < 8; ct++) {
      float sv = s[ct], sq = ss[ct];
      sv += __shfl_xor(sv, 16); sq += __shfl_xor(sq, 16);
      sv += __shfl_xor(sv, 32); sq += __shfl_xor(sq, 32);
      if (lg == 0) {
        atomicAdd(&red[ct * 16 + lr], sv);
        atomicAdd(&red[HD + ct * 16 + lr], sq);
      }
    }
    __syncthreads();
    float* st = stat + (blockIdx.x & 3) * 256;
    if (t < 2 * HD) atomicAdd(&st[t], red[t]);
  }
}

// ---------------- split-bf16 MFMA GEMM (contiguous, 64-row tile, 8 waves) ------
// R10's best-performing streaming GEMM: 33 KB LDS -> 4 blocks/CU x 512 thr =
// full occupancy. Wave = row-quarter x col-half; every 64B output line is fully
// covered by a single store instruction.
template<bool INBN, bool GATE, bool STATS>
__global__ __launch_bounds__(512, 8)
void gemm_split(const float* __restrict__ X, const unsigned short* __restrict__ Whi,
                const unsigned short* __restrict__ Wlo,
                const float* __restrict__ bias, const float* __restrict__ ab,
                const float* __restrict__ w2, float* __restrict__ outf,
                float* __restrict__ gate, float* __restrict__ stat, int Nn) {
  __shared__ unsigned short XsH[64 * HD];
  __shared__ unsigned short XsL[64 * HD];
  __shared__ float red[2 * HD];
  __shared__ float gred[64];
  int t = threadIdx.x;
  long rowbase = (long)blockIdx.x * 64;

#pragma unroll
  for (int it = 0; it < 4; it++) {
    int i = (t + it * 512) * 4;
    int r = i >> 7, k = i & (HD - 1);
    long row = rowbase + r; if (row > Nn - 1) row = Nn - 1;
    float4 v = *(const float4*)(X + row * HD + k);
    float f[4] = {v.x, v.y, v.z, v.w};
    if (INBN) {
#pragma unroll
      for (int j = 0; j < 4; j++)
        f[j] = fmaxf(f[j] * ab[k + j] + ab[HD + k + j], 0.f);
    }
    us4 hi, lo;
#pragma unroll
    for (int j = 0; j < 4; j++) {
      unsigned short hh = f2bf(f[j]);
      hi[j] = hh;
      lo[j] = f2bf(f[j] - bf2f(hh));
    }
    int g = k >> 3;
    int off = r * HD + ((((g ^ (r & 7)) << 3)) | (k & 7));
    *(us4*)(XsH + off) = hi;
    *(us4*)(XsL + off) = lo;
  }
  if (STATS && t < 2 * HD) red[t] = 0.f;
  if (GATE && t < 64) gred[t] = 0.f;
  __syncthreads();

  int w = t >> 6, l = t & 63;
  int lr = l & 15, lg = l >> 4;
  int wr = w & 3, wc = w >> 2;

  f32x4 acc[4];
#pragma unroll
  for (int ct = 0; ct < 4; ct++) acc[ct] = (f32x4){0.f, 0.f, 0.f, 0.f};

  bf16x8 aH[4], aL[4];
  int arow = wr * 16 + lr;
#pragma unroll
  for (int k4 = 0; k4 < 4; k4++) {
    int kg = k4 * 4 + lg;
    int off = arow * HD + (((kg ^ (arow & 7)) << 3));
    aH[k4] = *(bf16x8*)(XsH + off);
    aL[k4] = *(bf16x8*)(XsL + off);
  }
#pragma unroll
  for (int ct = 0; ct < 4; ct++) {
    int cg = wc * 4 + ct;
#pragma unroll
    for (int k4 = 0; k4 < 4; k4++) {
      int bo = (((cg << 2) + k4) * 64 + l) * 8;
      bf16x8 bH = *(const bf16x8*)(Whi + bo);
      bf16x8 bL = *(const bf16x8*)(Wlo + bo);
      acc[ct] = __builtin_amdgcn_mfma_f32_16x16x32_bf16(aH[k4], bH, acc[ct], 0, 0, 0);
      acc[ct] = __builtin_amdgcn_mfma_f32_16x16x32_bf16(aH[k4], bL, acc[ct], 0, 0, 0);
      acc[ct] = __builtin_amdgcn_mfma_f32_16x16x32_bf16(aL[k4], bH, acc[ct], 0, 0, 0);
    }
  }

  if (GATE) {
#pragma unroll
    for (int jj = 0; jj < 4; jj++) {
      float p = 0.f;
#pragma unroll
      for (int ct = 0; ct < 4; ct++) {
        int col = (wc * 4 + ct) * 16 + lr;
        float v = fmaxf(acc[ct][jj] + bias[col], 0.f);
        p += v * w2[col];
      }
      p += __shfl_xor(p, 1);
      p += __shfl_xor(p, 2);
      p += __shfl_xor(p, 4);
      p += __shfl_xor(p, 8);
      if (lr == 0) atomicAdd(&gred[wr * 16 + lg * 4 + jj], p);
    }
    __syncthreads();
    if (t < 64 && rowbase + t < Nn) gate[rowbase + t] = gred[t];
  } else {
    float s[4], ss[4];
#pragma unroll
    for (int ct = 0; ct < 4; ct++) { s[ct] = 0.f; ss[ct] = 0.f; }
#pragma unroll
    for (int jj = 0; jj < 4; jj++) {
      long row = rowbase + wr * 16 + lg * 4 + jj;
      bool ok = row < Nn;
#pragma unroll
      for (int ct = 0; ct < 4; ct++) {
        int col = (wc * 4 + ct) * 16 + lr;
        float v = acc[ct][jj] + bias[col];
        if (ok) {
          outf[row * HD + col] = v;
          if (STATS) { s[ct] += v; ss[ct] += v * v; }
        }
      }
    }
    if (STATS) {
#pragma unroll
      for (int ct = 0; ct < 4; ct++) {
        int col = (wc * 4 + ct) * 16 + lr;
        float sv = s[ct], sq = ss[ct];
        sv += __shfl_xor(sv, 16); sq += __shfl_xor(sq, 16);
        sv += __shfl_xor(sv, 32); sq += __shfl_xor(sq, 32);
        if (lg == 0) {
          atomicAdd(&red[col], sv);
          atomicAdd(&red[HD + col], sq);
        }
      }
      __syncthreads();
      float* st = stat + (blockIdx.x & 3) * 256;
      if (t < 2 * HD) atomicAdd(&st[t], red[t]);
    }
  }
}

__global__ void finalize_kernel(const float* __restrict__ stat, const float* __restrict__ g,
                                const float* __restrict__ be, float* ab, float inv_n) {
  int c = threadIdx.x;
  float s = stat[c] + stat[256 + c] + stat[512 + c] + stat[768 + c];
  float sq = stat[HD + c] + stat[256 + HD + c] + stat[512 + HD + c] + stat[768 + HD + c];
  float mean = s * inv_n;
  float var = sq * inv_n - mean * mean;
  float inv = rsqrtf(var + 1e-5f);
  float a = inv * g[c];
  ab[c] = a;
  ab[HD + c] = be[c] - mean * a;
}

__global__ void finalize1_kernel(const float* __restrict__ stat, const float* __restrict__ g,
                                 const float* __restrict__ be, float* ab, float inv_n) {
  int c = threadIdx.x;
  float mean = stat[c] * inv_n;
  float var = stat[HD + c] * inv_n - mean * mean;
  float inv = rsqrtf(var + 1e-5f);
  float a = inv * g[c];
  ab[c] = a;
  ab[HD + c] = be[c] - mean * a;
}

__global__ void bound_kernel(const int* __restrict__ batch, int* gs, int N, int G) {
  int i = blockIdx.x * blockDim.x + threadIdx.x;
  if (i >= N) return;
  int b = batch[i];
  int prev = (i == 0) ? -1 : batch[i - 1];
  for (int g = prev + 1; g <= b; g++) gs[g] = i;
  if (i == N - 1)
    for (int g = b + 1; g <= G; g++) gs[g] = N;
}

__global__ void fused_pool(const float* __restrict__ h, const float* __restrict__ gate,
                           const int* __restrict__ gs, const float* __restrict__ ab,
                           float* __restrict__ pooled) {
  int g = blockIdx.x;
  int t = threadIdx.x;
  int s0 = gs[g], s1 = gs[g + 1];
  if (s0 >= s1) { pooled[(size_t)g * HD + t] = 0.f; return; }
  __shared__ float red[HD];
  float m = -INFINITY;
  for (int i = s0 + t; i < s1; i += HD) m = fmaxf(m, gate[i]);
  red[t] = m;
  __syncthreads();
  for (int o = 64; o > 0; o >>= 1) {
    if (t < o) red[t] = fmaxf(red[t], red[t + o]);
    __syncthreads();
  }
  m = red[0];
  __syncthreads();
  float s = 0.f;
  for (int i = s0 + t; i < s1; i += HD) s += expf(gate[i] - m);
  red[t] = s;
  __syncthreads();
  for (int o = 64; o > 0; o >>= 1) {
    if (t < o) red[t] += red[t + o];
    __syncthreads();
  }
  float inv = 1.f / red[0];
  float a = ab[t], b = ab[HD + t];
  float acc = 0.f;
  int i = s0;
  for (; i + 4 <= s1; i += 4) {
    float al0 = expf(gate[i] - m);
    float al1 = expf(gate[i + 1] - m);
    float al2 = expf(gate[i + 2] - m);
    float al3 = expf(gate[i + 3] - m);
    float v0 = fmaxf(h[(size_t)(i + 0) * HD + t] * a + b, 0.f);
    float v1 = fmaxf(h[(size_t)(i + 1) * HD + t] * a + b, 0.f);
    float v2 = fmaxf(h[(size_t)(i + 2) * HD + t] * a + b, 0.f);
    float v3 = fmaxf(h[(size_t)(i + 3) * HD + t] * a + b, 0.f);
    acc += al0 * v0 + al1 * v1 + al2 * v2 + al3 * v3;
  }
  for (; i < s1; i++) {
    float al = expf(gate[i] - m);
    float v = fmaxf(h[(size_t)i * HD + t] * a + b, 0.f);
    acc += al * v;
  }
  pooled[(size_t)g * HD + t] = acc * inv;
}

// f32 classifier GEMM: zc[G x 128] = pooled @ W + bias
__global__ __launch_bounds__(256, 4)
void gemm_f32(const float* __restrict__ X, const float* __restrict__ W,
              const float* __restrict__ bias, float* __restrict__ out, int Nn) {
  __shared__ float XsT[32][132];
  __shared__ float Ws[32][HD];
  int t = threadIdx.x;
  int r0 = (t >> 4) * 8;
  int c0 = (t & 15) * 8;
  long rowbase = (long)blockIdx.x * 128;

  float acc[8][8];
#pragma unroll
  for (int ci = 0; ci < 8; ci++) {
    float bv = bias[c0 + ci];
#pragma unroll
    for (int ri = 0; ri < 8; ri++) acc[ri][ci] = bv;
  }

  int sr = t >> 1;
  int hf = t & 1;
  long srow = rowbase + sr; if (srow > Nn - 1) srow = Nn - 1;
  const float* xrow = X + srow * HD;

  for (int k0 = 0; k0 < HD; k0 += 32) {
    __syncthreads();
#pragma unroll
    for (int j = 0; j < 4; j++) {
      int i = j * 1024 + t * 4;
      int kk = i >> 7, c = i & (HD - 1);
      *(float4*)&Ws[kk][c] = *(const float4*)&W[(size_t)(k0 + kk) * HD + c];
    }
#pragma unroll
    for (int j = 0; j < 4; j++) {
      int kc = k0 + hf * 16 + j * 4;
      float4 v = *(const float4*)&xrow[kc];
      int kl = hf * 16 + j * 4;
      XsT[kl + 0][sr] = v.x;
      XsT[kl + 1][sr] = v.y;
      XsT[kl + 2][sr] = v.z;
      XsT[kl + 3][sr] = v.w;
    }
    __syncthreads();
#pragma unroll 8
    for (int kk = 0; kk < 32; kk++) {
      float4 a0 = *(float4*)&XsT[kk][r0];
      float4 a1 = *(float4*)&XsT[kk][r0 + 4];
      float4 b0 = *(float4*)&Ws[kk][c0];
      float4 b1 = *(float4*)&Ws[kk][c0 + 4];
      float ar[8] = {a0.x, a0.y, a0.z, a0.w, a1.x, a1.y, a1.z, a1.w};
      float bc[8] = {b0.x, b0.y, b0.z, b0.w, b1.x, b1.y, b1.z, b1.w};
#pragma unroll
      for (int ri = 0; ri < 8; ri++)
#pragma unroll
        for (int ci = 0; ci < 8; ci++) acc[ri][ci] += ar[ri] * bc[ci];
    }
  }

#pragma unroll
  for (int ri = 0; ri < 8; ri++) {
    long row = rowbase + r0 + ri;
    if (row < Nn) {
      float4 o0 = {acc[ri][0], acc[ri][1], acc[ri][2], acc[ri][3]};
      float4 o1 = {acc[ri][4], acc[ri][5], acc[ri][6], acc[ri][7]};
      *(float4*)&out[row * HD + c0] = o0;
      *(float4*)&out[row * HD + c0 + 4] = o1;
    }
  }
}

__global__ void stats_f32(const float* __restrict__ z, float* stat, int n) {
  int c = threadIdx.x & (HD - 1);
  int rg = threadIdx.x >> 7;
  float s = 0.f, ss = 0.f;
  for (int r = blockIdx.x * 2 + rg; r < n; r += gridDim.x * 2) {
    float v = z[(size_t)r * HD + c];
    s += v; ss += v * v;
  }
  __shared__ float S[2][HD], SS[2][HD];
  S[rg][c] = s; SS[rg][c] = ss;
  __syncthreads();
  if (threadIdx.x < HD) {
    atomicAdd(&stat[c], S[0][c] + S[1][c]);
    atomicAdd(&stat[HD + c], SS[0][c] + SS[1][c]);
  }
}

__global__ void cls_out_kernel(const float* __restrict__ zc, const float* __restrict__ ab,
                               const float* __restrict__ W2, const float* __restrict__ b2,
                               float* out, int G) {
  int row = blockIdx.x;
  int t = threadIdx.x;
  float v0 = fmaxf(zc[(size_t)row * HD + t] * ab[t] + ab[HD + t], 0.f);
  float v1 = fmaxf(zc[(size_t)row * HD + 64 + t] * ab[64 + t] + ab[HD + 64 + t], 0.f);
  for (int o = 0; o < 10; o++) {
    float p = v0 * W2[t * 10 + o] + v1 * W2[(64 + t) * 10 + o];
#pragma unroll
    for (int s = 32; s > 0; s >>= 1) p += __shfl_down(p, s);
    if (t == 0) out[row * 10 + o] = p + b2[o];
  }
}

extern "C" void kernel_launch(void* const* d_in, const int* in_sizes, int n_in,
                              void* d_out, int out_size, void* d_ws, size_t ws_size,
                              hipStream_t stream) {
  const int* x     = (const int*)d_in[0];
  const int* ei    = (const int*)d_in[1];
  const int* batch = (const int*)d_in[2];
  const float* pe  = (const float*)d_in[4];
  const float* ce  = (const float*)d_in[5];
  const float* le  = (const float*)d_in[6];
  const float* cW1 = (const float*)d_in[7];
  const float* cb1 = (const float*)d_in[8];
  const float* cg1 = (const float*)d_in[9];
  const float* cbe1= (const float*)d_in[10];
  const float* cW2 = (const float*)d_in[11];
  const float* cb2 = (const float*)d_in[12];
  const float* ngm = (const float*)d_in[13];
  const float* nbe = (const float*)d_in[14];
  const float* gW1 = (const float*)d_in[15];
  const float* gb1 = (const float*)d_in[16];
  const float* gW2 = (const float*)d_in[17];
  const float* clW1= (const float*)d_in[19];
  const float* clb1= (const float*)d_in[20];
  const float* clg = (const float*)d_in[21];
  const float* clbe= (const float*)d_in[22];
  const float* clW2= (const float*)d_in[23];
  const float* clb2= (const float*)d_in[24];

  int N = in_sizes[2];
  int E = in_sizes[1] / 2;
  int G = out_size / 10;

  float* buf0   = (float*)d_ws;              // h (f32)
  float* buf1   = buf0 + (size_t)N * HD;     // z (f32)
  float* pooled = buf1 + (size_t)N * HD;     // G x 128
  float* gate   = pooled + (size_t)G * HD;   // N
  float* zc     = gate + N;                  // G x 128
  float* stats  = zc + (size_t)G * HD;       // 7 x 1024
  float* ab     = stats + 7 * 1024;          // 7 x 256
  unsigned short* whi = (unsigned short*)(ab + 7 * 256);  // 7 x 128 x 128 bf16
  unsigned short* wlo = whi + 7 * HD * HD;
  int* csr_off  = (int*)(wlo + 7 * HD * HD); // N+1
  int* cursor   = csr_off + (N + 1);         // N
  int* bsum     = cursor + N;                // 128
  int* gs       = bsum + 128;                // G+1
  int* csr_src  = gs + (G + 1);              // E

  float* out = (float*)d_out;
  int gatherBlocks = (N + 127) / 128;
  int splitBlocks  = (N + 63) / 64;
  int Wwin = (N + 7) / 8;

  zero_f<<<28, 256, 0, stream>>>(stats, 7 * 1024);
  encode_kernel<<<2048, 256, 0, stream>>>(x, pe, ce, le, buf0, N);
  prep_w<<<7, 256, 0, stream>>>(cW1, cW2, gW1, whi, wlo);

  // CSR build (XCD-owned dst windows; reused by all 3 layers)
  int nb = (N + SCAN_BS - 1) / SCAN_BS;
  zero_int<<<256, 256, 0, stream>>>(cursor, N);
  hist_kernel<<<2048, 256, 0, stream>>>(ei, cursor, E, Wwin);
  scan1_kernel<<<nb, 256, 0, stream>>>(cursor, csr_off, bsum, N);
  scan2_kernel<<<1, 128, 0, stream>>>(bsum, nb);
  scan3_kernel<<<256, 256, 0, stream>>>(csr_off, cursor, bsum, N, E);
  fill_kernel<<<2048, 256, 0, stream>>>(ei, cursor, csr_src, E, Wwin);
  bound_kernel<<<(N + 255) / 256, 256, 0, stream>>>(batch, gs, N, G);

  for (int l = 0; l < 3; l++) {
    float* abPrev = ab + (l - 1) * 512 + 256;
    if (l == 0)
      gemm_gather<false, true><<<gatherBlocks, 512, 0, stream>>>(
          buf0, csr_off, csr_src, nullptr,
          whi + (size_t)l * HD * HD, wlo + (size_t)l * HD * HD,
          cb1 + l * HD, buf1, stats + l * 2048, N);
    else
      gemm_gather<true, true><<<gatherBlocks, 512, 0, stream>>>(
          buf0, csr_off, csr_src, abPrev,
          whi + (size_t)l * HD * HD, wlo + (size_t)l * HD * HD,
          cb1 + l * HD, buf1, stats + l * 2048, N);
    finalize_kernel<<<1, 128, 0, stream>>>(stats + l * 2048, cg1 + l * HD, cbe1 + l * HD,
                                           ab + l * 512, 1.f / N);
    gemm_split<true, false, true><<<splitBlocks, 512, 0, stream>>>(
        buf1, whi + (size_t)(3 + l) * HD * HD, wlo + (size_t)(3 + l) * HD * HD,
        cb2 + l * HD, ab + l * 512, nullptr, buf0, nullptr, stats + l * 2048 + 1024, N);
    finalize_kernel<<<1, 128, 0, stream>>>(stats + l * 2048 + 1024, ngm + l * HD, nbe + l * HD,
                                           ab + l * 512 + 256, 1.f / N);
  }

  const float* abFin = ab + 2 * 512 + 256;
  gemm_split<true, true, false><<<splitBlocks, 512, 0, stream>>>(
      buf0, whi + (size_t)6 * HD * HD, wlo + (size_t)6 * HD * HD,
      gb1, abFin, gW2, nullptr, gate, nullptr, N);
  fused_pool<<<G, HD, 0, stream>>>(buf0, gate, gs, abFin, pooled);

  // classifier tail in f32
  gemm_f32<<<(G + 127) / 128, 256, 0, stream>>>(pooled, clW1, clb1, zc, G);
  stats_f32<<<64, 256, 0, stream>>>(zc, stats + 6 * 1024, G);
  finalize1_kernel<<<1, 128, 0, stream>>>(stats + 6 * 1024, clg, clbe, ab + 6 * 256, 1.f / G);
  cls_out_kernel<<<G, 64, 0, stream>>>(zc, ab + 6 * 256, clW2, clb2, out, G);
}

// Round 13
// 774.312 us; speedup vs baseline: 1.1970x; 1.1078x over previous
//
#include <hip/hip_runtime.h>
#include <math.h>

#define HD 128

typedef __attribute__((ext_vector_type(8))) short bf16x8;
typedef __attribute__((ext_vector_type(8))) unsigned short us8;
typedef __attribute__((ext_vector_type(4))) unsigned short us4;
typedef __attribute__((ext_vector_type(4))) float f32x4;

__device__ __forceinline__ float bf2f(unsigned short u) {
  union { unsigned int i; float f; } v; v.i = ((unsigned int)u) << 16; return v.f;
}
__device__ __forceinline__ unsigned short f2bf(float f) {
  union { float f; unsigned int i; } v; v.f = f;
  unsigned int u = v.i;
  u += 0x7FFFu + ((u >> 16) & 1u);
  return (unsigned short)(u >> 16);
}

__global__ void zero_f(float* p, int n) {
  int i = blockIdx.x * blockDim.x + threadIdx.x;
  if (i < n) p[i] = 0.f;
}

__global__ void zero_int(int* p, int n) {
  int stride = gridDim.x * blockDim.x;
  for (int i = blockIdx.x * blockDim.x + threadIdx.x; i < n; i += stride) p[i] = 0;
}

__global__ void encode_kernel(const int* __restrict__ x, const float* __restrict__ pe,
                              const float* __restrict__ ce, const float* __restrict__ le,
                              float* __restrict__ h, unsigned short* __restrict__ hb, int n) {
  int total = n * HD;
  int stride = gridDim.x * blockDim.x;
  for (int idx = blockIdx.x * blockDim.x + threadIdx.x; idx < total; idx += stride) {
    int node = idx >> 7, c = idx & (HD - 1);
    int lv = x[node * 3 + 0]; lv = lv < 0 ? 0 : (lv > 999 ? 999 : lv);
    int ct = x[node * 3 + 1]; ct = ct < 0 ? 0 : (ct > 4 ? 4 : ct);
    int th = x[node * 3 + 2]; th = th < 0 ? 0 : (th > 4999 ? 4999 : th);
    float v = ce[ct * HD + c] + le[lv * HD + c] + pe[th * HD + c];
    h[idx] = v;
    hb[idx] = f2bf(v);
  }
}

// split 7 [128][128] f32 weight mats into bf16 hi/lo in WAVE-TILED fragment layout
__global__ void prep_w(const float* __restrict__ cW1, const float* __restrict__ cW2,
                       const float* __restrict__ gW1,
                       unsigned short* __restrict__ whi, unsigned short* __restrict__ wlo) {
  int m = blockIdx.x;
  const float* W = (m < 3) ? cW1 + (size_t)m * HD * HD
                 : (m < 6) ? cW2 + (size_t)(m - 3) * HD * HD : gW1;
  unsigned short* oh = whi + (size_t)m * HD * HD;
  unsigned short* ol = wlo + (size_t)m * HD * HD;
  for (int i = threadIdx.x; i < HD * HD; i += 256) {
    int j = i & 7;
    int l = (i >> 3) & 63;
    int p = i >> 9;
    int cg = p >> 2, k4 = p & 3;
    int c = cg * 16 + (l & 15);
    int k = (k4 * 4 + (l >> 4)) * 8 + j;
    float f = W[k * HD + c];
    unsigned short hh = f2bf(f);
    oh[i] = hh;
    ol[i] = f2bf(f - bf2f(hh));
  }
}

// ---------------- CSR build (XCD-owned dst windows) -----------------------------

__global__ void hist_kernel(const int* __restrict__ ei, int* deg, int E, int Wwin) {
  int pass = blockIdx.x & 7;
  int b = blockIdx.x >> 3;
  int tstride = (gridDim.x >> 3) * blockDim.x;
  for (int e = b * blockDim.x + threadIdx.x; e < E; e += tstride) {
    int d = ei[E + e];
    if (d / Wwin == pass) atomicAdd(&deg[d], 1);
  }
}

#define SCAN_BS 1024
__global__ void scan1_kernel(const int* __restrict__ deg, int* __restrict__ off,
                             int* __restrict__ bsum, int n) {
  __shared__ int sh[256];
  int b = blockIdx.x, t = threadIdx.x;
  int base = b * SCAN_BS + t * 4;
  int v[4];
#pragma unroll
  for (int j = 0; j < 4; j++) v[j] = (base + j < n) ? deg[base + j] : 0;
  int s = v[0] + v[1] + v[2] + v[3];
  sh[t] = s;
  __syncthreads();
  for (int o = 1; o < 256; o <<= 1) {
    int x = (t >= o) ? sh[t - o] : 0;
    __syncthreads();
    sh[t] += x;
    __syncthreads();
  }
  int excl = sh[t] - s;
  if (t == 255) bsum[b] = sh[255];
  int run = excl;
#pragma unroll
  for (int j = 0; j < 4; j++) {
    if (base + j < n) off[base + j] = run;
    run += v[j];
  }
}

__global__ void scan2_kernel(int* bsum, int nb) {
  __shared__ int sh[128];
  int t = threadIdx.x;
  int v = (t < nb) ? bsum[t] : 0;
  sh[t] = v;
  __syncthreads();
  for (int o = 1; o < 128; o <<= 1) {
    int x = (t >= o) ? sh[t - o] : 0;
    __syncthreads();
    sh[t] += x;
    __syncthreads();
  }
  if (t < nb) bsum[t] = sh[t] - v;
}

__global__ void scan3_kernel(int* off, int* cursor, const int* __restrict__ bsum,
                             int n, int E) {
  int idx = blockIdx.x * blockDim.x + threadIdx.x;
  int stride = gridDim.x * blockDim.x;
  for (int i = idx; i < n; i += stride) {
    int v = off[i] + bsum[i >> 10];
    off[i] = v;
    cursor[i] = v;
  }
  if (idx == 0) off[n] = E;
}

__global__ void fill_kernel(const int* __restrict__ ei, int* cursor, int* csr_src,
                            int E, int Wwin) {
  int pass = blockIdx.x & 7;
  int b = blockIdx.x >> 3;
  int tstride = (gridDim.x >> 3) * blockDim.x;
  for (int e = b * blockDim.x + threadIdx.x; e < E; e += tstride) {
    int d = ei[E + e];
    if (d / Wwin == pass) {
      int pos = atomicAdd(&cursor[d], 1);
      csr_src[pos] = ei[e];
    }
  }
}

// ---------------- fused gather + split-bf16 MFMA GEMM (128-row tile) -----------
// Neighbors read from the bf16 shadow copy hb (256B/row: half bytes + half line
// requests vs f32); self-term stays f32. BN+ReLU applied in f32 after upconvert.
template<bool BN, bool STATS>
__global__ __launch_bounds__(512, 4)
void gemm_gather(const float* __restrict__ h, const unsigned short* __restrict__ hb,
                 const int* __restrict__ off,
                 const int* __restrict__ src, const float* __restrict__ ab,
                 const unsigned short* __restrict__ Whi,
                 const unsigned short* __restrict__ Wlo,
                 const float* __restrict__ bias, float* __restrict__ outf,
                 float* __restrict__ stat, int Nn) {
  __shared__ unsigned short XsH[128 * HD];
  __shared__ unsigned short XsL[128 * HD];
  __shared__ float red[2 * HD];
  int t = threadIdx.x;
  long rowbase = (long)blockIdx.x * 128;
  int grp = t >> 5, lane = t & 31;

  float4 a4, b4;
  if (BN) {
    a4 = *(const float4*)(ab + lane * 4);
    b4 = *(const float4*)(ab + HD + lane * 4);
  }
#define APPLY_BN(v) if (BN) { \
    v.x = fmaxf(v.x * a4.x + b4.x, 0.f); \
    v.y = fmaxf(v.y * a4.y + b4.y, 0.f); \
    v.z = fmaxf(v.z * a4.z + b4.z, 0.f); \
    v.w = fmaxf(v.w * a4.w + b4.w, 0.f); }
#define UP4(wv) {bf2f(wv[0]), bf2f(wv[1]), bf2f(wv[2]), bf2f(wv[3])}

  // gather phase: 16 groups x 32 lanes; 8 rows/group; 8-deep edge unroll
  for (int rr = 0; rr < 8; rr++) {
    int r = grp + rr * 16;
    long row = rowbase + r; if (row > Nn - 1) row = Nn - 1;
    int s0 = off[row], s1 = off[row + 1];
    float4 acc0 = *(const float4*)(h + row * HD + lane * 4);
    APPLY_BN(acc0);
    float4 acc1 = {0.f, 0.f, 0.f, 0.f};
    float4 acc2 = {0.f, 0.f, 0.f, 0.f};
    float4 acc3 = {0.f, 0.f, 0.f, 0.f};
    int e = s0;
    for (; e + 8 <= s1; e += 8) {
      int i0 = src[e], i1 = src[e + 1], i2 = src[e + 2], i3 = src[e + 3];
      int i4 = src[e + 4], i5 = src[e + 5], i6 = src[e + 6], i7 = src[e + 7];
      us4 w0 = *(const us4*)(hb + (size_t)i0 * HD + lane * 4);
      us4 w1 = *(const us4*)(hb + (size_t)i1 * HD + lane * 4);
      us4 w2 = *(const us4*)(hb + (size_t)i2 * HD + lane * 4);
      us4 w3 = *(const us4*)(hb + (size_t)i3 * HD + lane * 4);
      us4 w4 = *(const us4*)(hb + (size_t)i4 * HD + lane * 4);
      us4 w5 = *(const us4*)(hb + (size_t)i5 * HD + lane * 4);
      us4 w6 = *(const us4*)(hb + (size_t)i6 * HD + lane * 4);
      us4 w7 = *(const us4*)(hb + (size_t)i7 * HD + lane * 4);
      float4 v0 = UP4(w0), v1 = UP4(w1), v2 = UP4(w2), v3 = UP4(w3);
      float4 v4 = UP4(w4), v5 = UP4(w5), v6 = UP4(w6), v7 = UP4(w7);
      APPLY_BN(v0); APPLY_BN(v1); APPLY_BN(v2); APPLY_BN(v3);
      APPLY_BN(v4); APPLY_BN(v5); APPLY_BN(v6); APPLY_BN(v7);
      acc0.x += v0.x + v4.x; acc0.y += v0.y + v4.y; acc0.z += v0.z + v4.z; acc0.w += v0.w + v4.w;
      acc1.x += v1.x + v5.x; acc1.y += v1.y + v5.y; acc1.z += v1.z + v5.z; acc1.w += v1.w + v5.w;
      acc2.x += v2.x + v6.x; acc2.y += v2.y + v6.y; acc2.z += v2.z + v6.z; acc2.w += v2.w + v6.w;
      acc3.x += v3.x + v7.x; acc3.y += v3.y + v7.y; acc3.z += v3.z + v7.z; acc3.w += v3.w + v7.w;
    }
    for (; e < s1; e++) {
      int s = src[e];
      us4 wv = *(const us4*)(hb + (size_t)s * HD + lane * 4);
      float4 v = UP4(wv);
      APPLY_BN(v);
      acc0.x += v.x; acc0.y += v.y; acc0.z += v.z; acc0.w += v.w;
    }
    acc0.x += acc1.x + acc2.x + acc3.x;
    acc0.y += acc1.y + acc2.y + acc3.y;
    acc0.z += acc1.z + acc2.z + acc3.z;
    acc0.w += acc1.w + acc2.w + acc3.w;
    float f[4] = {acc0.x, acc0.y, acc0.z, acc0.w};
    us4 hi, lo;
#pragma unroll
    for (int j = 0; j < 4; j++) {
      unsigned short hh = f2bf(f[j]);
      hi[j] = hh;
      lo[j] = f2bf(f[j] - bf2f(hh));
    }
    int g8 = lane >> 1;
    int offl = r * HD + (((g8 ^ (r & 7)) << 3)) + (lane & 1) * 4;
    *(us4*)(XsH + offl) = hi;
    *(us4*)(XsL + offl) = lo;
  }
#undef APPLY_BN
#undef UP4
  if (STATS && t < 2 * HD) red[t] = 0.f;
  __syncthreads();

  int w = t >> 6, l = t & 63;
  int lr = l & 15, lg = l >> 4;

  f32x4 acc[8];
#pragma unroll
  for (int ct = 0; ct < 8; ct++) acc[ct] = (f32x4){0.f, 0.f, 0.f, 0.f};

  bf16x8 aH[4], aL[4];
  int arow = w * 16 + lr;
#pragma unroll
  for (int k4 = 0; k4 < 4; k4++) {
    int kg = k4 * 4 + lg;
    int offa = arow * HD + (((kg ^ (arow & 7)) << 3));
    aH[k4] = *(bf16x8*)(XsH + offa);
    aL[k4] = *(bf16x8*)(XsL + offa);
  }
#pragma unroll
  for (int ct = 0; ct < 8; ct++) {
#pragma unroll
    for (int k4 = 0; k4 < 4; k4++) {
      int bo = (((ct << 2) + k4) * 64 + l) * 8;
      bf16x8 bH = *(const bf16x8*)(Whi + bo);
      bf16x8 bL = *(const bf16x8*)(Wlo + bo);
      acc[ct] = __builtin_amdgcn_mfma_f32_16x16x32_bf16(aH[k4], bH, acc[ct], 0, 0, 0);
      acc[ct] = __builtin_amdgcn_mfma_f32_16x16x32_bf16(aH[k4], bL, acc[ct], 0, 0, 0);
      acc[ct] = __builtin_amdgcn_mfma_f32_16x16x32_bf16(aL[k4], bH, acc[ct], 0, 0, 0);
    }
  }

  float s[8], ss[8];
#pragma unroll
  for (int ct = 0; ct < 8; ct++) { s[ct] = 0.f; ss[ct] = 0.f; }
#pragma unroll
  for (int jj = 0; jj < 4; jj++) {
    long row = rowbase + w * 16 + lg * 4 + jj;
    bool ok = row < Nn;
#pragma unroll
    for (int ct = 0; ct < 8; ct++) {
      float v = acc[ct][jj] + bias[ct * 16 + lr];
      if (ok) {
        outf[row * HD + ct * 16 + lr] = v;
        if (STATS) { s[ct] += v; ss[ct] += v * v; }
      }
    }
  }
  if (STATS) {
#pragma unroll
    for (int ct = 0; ct < 8; ct++) {
      float sv = s[ct], sq = ss[ct];
      sv += __shfl_xor(sv, 16); sq += __shfl_xor(sq, 16);
      sv += __shfl_xor(sv, 32); sq += __shfl_xor(sq, 32);
      if (lg == 0) {
        atomicAdd(&red[ct * 16 + lr], sv);
        atomicAdd(&red[HD + ct * 16 + lr], sq);
      }
    }
    __syncthreads();
    float* st = stat + (blockIdx.x & 3) * 256;
    if (t < 2 * HD) atomicAdd(&st[t], red[t]);
  }
}

// ---------------- split-bf16 MFMA GEMM (contiguous, 64-row tile, 8 waves) ------
// Optionally emits a bf16 shadow copy of the f32 output (for next layer's gather).
template<bool INBN, bool GATE, bool STATS>
__global__ __launch_bounds__(512, 8)
void gemm_split(const float* __restrict__ X, const unsigned short* __restrict__ Whi,
                const unsigned short* __restrict__ Wlo,
                const float* __restrict__ bias, const float* __restrict__ ab,
                const float* __restrict__ w2, float* __restrict__ outf,
                unsigned short* __restrict__ outb,
                float* __restrict__ gate, float* __restrict__ stat, int Nn) {
  __shared__ unsigned short XsH[64 * HD];
  __shared__ unsigned short XsL[64 * HD];
  __shared__ float red[2 * HD];
  __shared__ float gred[64];
  int t = threadIdx.x;
  long rowbase = (long)blockIdx.x * 64;

#pragma unroll
  for (int it = 0; it < 4; it++) {
    int i = (t + it * 512) * 4;
    int r = i >> 7, k = i & (HD - 1);
    long row = rowbase + r; if (row > Nn - 1) row = Nn - 1;
    float4 v = *(const float4*)(X + row * HD + k);
    float f[4] = {v.x, v.y, v.z, v.w};
    if (INBN) {
#pragma unroll
      for (int j = 0; j < 4; j++)
        f[j] = fmaxf(f[j] * ab[k + j] + ab[HD + k + j], 0.f);
    }
    us4 hi, lo;
#pragma unroll
    for (int j = 0; j < 4; j++) {
      unsigned short hh = f2bf(f[j]);
      hi[j] = hh;
      lo[j] = f2bf(f[j] - bf2f(hh));
    }
    int g = k >> 3;
    int off = r * HD + ((((g ^ (r & 7)) << 3)) | (k & 7));
    *(us4*)(XsH + off) = hi;
    *(us4*)(XsL + off) = lo;
  }
  if (STATS && t < 2 * HD) red[t] = 0.f;
  if (GATE && t < 64) gred[t] = 0.f;
  __syncthreads();

  int w = t >> 6, l = t & 63;
  int lr = l & 15, lg = l >> 4;
  int wr = w & 3, wc = w >> 2;

  f32x4 acc[4];
#pragma unroll
  for (int ct = 0; ct < 4; ct++) acc[ct] = (f32x4){0.f, 0.f, 0.f, 0.f};

  bf16x8 aH[4], aL[4];
  int arow = wr * 16 + lr;
#pragma unroll
  for (int k4 = 0; k4 < 4; k4++) {
    int kg = k4 * 4 + lg;
    int off = arow * HD + (((kg ^ (arow & 7)) << 3));
    aH[k4] = *(bf16x8*)(XsH + off);
    aL[k4] = *(bf16x8*)(XsL + off);
  }
#pragma unroll
  for (int ct = 0; ct < 4; ct++) {
    int cg = wc * 4 + ct;
#pragma unroll
    for (int k4 = 0; k4 < 4; k4++) {
      int bo = (((cg << 2) + k4) * 64 + l) * 8;
      bf16x8 bH = *(const bf16x8*)(Whi + bo);
      bf16x8 bL = *(const bf16x8*)(Wlo + bo);
      acc[ct] = __builtin_amdgcn_mfma_f32_16x16x32_bf16(aH[k4], bH, acc[ct], 0, 0, 0);
      acc[ct] = __builtin_amdgcn_mfma_f32_16x16x32_bf16(aH[k4], bL, acc[ct], 0, 0, 0);
      acc[ct] = __builtin_amdgcn_mfma_f32_16x16x32_bf16(aL[k4], bH, acc[ct], 0, 0, 0);
    }
  }

  if (GATE) {
#pragma unroll
    for (int jj = 0; jj < 4; jj++) {
      float p = 0.f;
#pragma unroll
      for (int ct = 0; ct < 4; ct++) {
        int col = (wc * 4 + ct) * 16 + lr;
        float v = fmaxf(acc[ct][jj] + bias[col], 0.f);
        p += v * w2[col];
      }
      p += __shfl_xor(p, 1);
      p += __shfl_xor(p, 2);
      p += __shfl_xor(p, 4);
      p += __shfl_xor(p, 8);
      if (lr == 0) atomicAdd(&gred[wr * 16 + lg * 4 + jj], p);
    }
    __syncthreads();
    if (t < 64 && rowbase + t < Nn) gate[rowbase + t] = gred[t];
  } else {
    float s[4], ss[4];
#pragma unroll
    for (int ct = 0; ct < 4; ct++) { s[ct] = 0.f; ss[ct] = 0.f; }
#pragma unroll
    for (int jj = 0; jj < 4; jj++) {
      long row = rowbase + wr * 16 + lg * 4 + jj;
      bool ok = row < Nn;
#pragma unroll
      for (int ct = 0; ct < 4; ct++) {
        int col = (wc * 4 + ct) * 16 + lr;
        float v = acc[ct][jj] + bias[col];
        if (ok) {
          outf[row * HD + col] = v;
          if (outb) outb[row * HD + col] = f2bf(v);
          if (STATS) { s[ct] += v; ss[ct] += v * v; }
        }
      }
    }
    if (STATS) {
#pragma unroll
      for (int ct = 0; ct < 4; ct++) {
        int col = (wc * 4 + ct) * 16 + lr;
        float sv = s[ct], sq = ss[ct];
        sv += __shfl_xor(sv, 16); sq += __shfl_xor(sq, 16);
        sv += __shfl_xor(sv, 32); sq += __shfl_xor(sq, 32);
        if (lg == 0) {
          atomicAdd(&red[col], sv);
          atomicAdd(&red[HD + col], sq);
        }
      }
      __syncthreads();
      float* st = stat + (blockIdx.x & 3) * 256;
      if (t < 2 * HD) atomicAdd(&st[t], red[t]);
    }
  }
}

__global__ void finalize_kernel(const float* __restrict__ stat, const float* __restrict__ g,
                                const float* __restrict__ be, float* ab, float inv_n) {
  int c = threadIdx.x;
  float s = stat[c] + stat[256 + c] + stat[512 + c] + stat[768 + c];
  float sq = stat[HD + c] + stat[256 + HD + c] + stat[512 + HD + c] + stat[768 + HD + c];
  float mean = s * inv_n;
  float var = sq * inv_n - mean * mean;
  float inv = rsqrtf(var + 1e-5f);
  float a = inv * g[c];
  ab[c] = a;
  ab[HD + c] = be[c] - mean * a;
}

__global__ void finalize1_kernel(const float* __restrict__ stat, const float* __restrict__ g,
                                 const float* __restrict__ be, float* ab, float inv_n) {
  int c = threadIdx.x;
  float mean = stat[c] * inv_n;
  float var = stat[HD + c] * inv_n - mean * mean;
  float inv = rsqrtf(var + 1e-5f);
  float a = inv * g[c];
  ab[c] = a;
  ab[HD + c] = be[c] - mean * a;
}

__global__ void bound_kernel(const int* __restrict__ batch, int* gs, int N, int G) {
  int i = blockIdx.x * blockDim.x + threadIdx.x;
  if (i >= N) return;
  int b = batch[i];
  int prev = (i == 0) ? -1 : batch[i - 1];
  for (int g = prev + 1; g <= b; g++) gs[g] = i;
  if (i == N - 1)
    for (int g = b + 1; g <= G; g++) gs[g] = N;
}

__global__ void fused_pool(const float* __restrict__ h, const float* __restrict__ gate,
                           const int* __restrict__ gs, const float* __restrict__ ab,
                           float* __restrict__ pooled) {
  int g = blockIdx.x;
  int t = threadIdx.x;
  int s0 = gs[g], s1 = gs[g + 1];
  if (s0 >= s1) { pooled[(size_t)g * HD + t] = 0.f; return; }
  __shared__ float red[HD];
  float m = -INFINITY;
  for (int i = s0 + t; i < s1; i += HD) m = fmaxf(m, gate[i]);
  red[t] = m;
  __syncthreads();
  for (int o = 64; o > 0; o >>= 1) {
    if (t < o) red[t] = fmaxf(red[t], red[t + o]);
    __syncthreads();
  }
  m = red[0];
  __syncthreads();
  float s = 0.f;
  for (int i = s0 + t; i < s1; i += HD) s += expf(gate[i] - m);
  red[t] = s;
  __syncthreads();
  for (int o = 64; o > 0; o >>= 1) {
    if (t < o) red[t] += red[t + o];
    __syncthreads();
  }
  float inv = 1.f / red[0];
  float a = ab[t], b = ab[HD + t];
  float acc = 0.f;
  int i = s0;
  for (; i + 4 <= s1; i += 4) {
    float al0 = expf(gate[i] - m);
    float al1 = expf(gate[i + 1] - m);
    float al2 = expf(gate[i + 2] - m);
    float al3 = expf(gate[i + 3] - m);
    float v0 = fmaxf(h[(size_t)(i + 0) * HD + t] * a + b, 0.f);
    float v1 = fmaxf(h[(size_t)(i + 1) * HD + t] * a + b, 0.f);
    float v2 = fmaxf(h[(size_t)(i + 2) * HD + t] * a + b, 0.f);
    float v3 = fmaxf(h[(size_t)(i + 3) * HD + t] * a + b, 0.f);
    acc += al0 * v0 + al1 * v1 + al2 * v2 + al3 * v3;
  }
  for (; i < s1; i++) {
    float al = expf(gate[i] - m);
    float v = fmaxf(h[(size_t)i * HD + t] * a + b, 0.f);
    acc += al * v;
  }
  pooled[(size_t)g * HD + t] = acc * inv;
}

// f32 classifier GEMM: zc[G x 128] = pooled @ W + bias
__global__ __launch_bounds__(256, 4)
void gemm_f32(const float* __restrict__ X, const float* __restrict__ W,
              const float* __restrict__ bias, float* __restrict__ out, int Nn) {
  __shared__ float XsT[32][132];
  __shared__ float Ws[32][HD];
  int t = threadIdx.x;
  int r0 = (t >> 4) * 8;
  int c0 = (t & 15) * 8;
  long rowbase = (long)blockIdx.x * 128;

  float acc[8][8];
#pragma unroll
  for (int ci = 0; ci < 8; ci++) {
    float bv = bias[c0 + ci];
#pragma unroll
    for (int ri = 0; ri < 8; ri++) acc[ri][ci] = bv;
  }

  int sr = t >> 1;
  int hf = t & 1;
  long srow = rowbase + sr; if (srow > Nn - 1) srow = Nn - 1;
  const float* xrow = X + srow * HD;

  for (int k0 = 0; k0 < HD; k0 += 32) {
    __syncthreads();
#pragma unroll
    for (int j = 0; j < 4; j++) {
      int i = j * 1024 + t * 4;
      int kk = i >> 7, c = i & (HD - 1);
      *(float4*)&Ws[kk][c] = *(const float4*)&W[(size_t)(k0 + kk) * HD + c];
    }
#pragma unroll
    for (int j = 0; j < 4; j++) {
      int kc = k0 + hf * 16 + j * 4;
      float4 v = *(const float4*)&xrow[kc];
      int kl = hf * 16 + j * 4;
      XsT[kl + 0][sr] = v.x;
      XsT[kl + 1][sr] = v.y;
      XsT[kl + 2][sr] = v.z;
      XsT[kl + 3][sr] = v.w;
    }
    __syncthreads();
#pragma unroll 8
    for (int kk = 0; kk < 32; kk++) {
      float4 a0 = *(float4*)&XsT[kk][r0];
      float4 a1 = *(float4*)&XsT[kk][r0 + 4];
      float4 b0 = *(float4*)&Ws[kk][c0];
      float4 b1 = *(float4*)&Ws[kk][c0 + 4];
      float ar[8] = {a0.x, a0.y, a0.z, a0.w, a1.x, a1.y, a1.z, a1.w};
      float bc[8] = {b0.x, b0.y, b0.z, b0.w, b1.x, b1.y, b1.z, b1.w};
#pragma unroll
      for (int ri = 0; ri < 8; ri++)
#pragma unroll
        for (int ci = 0; ci < 8; ci++) acc[ri][ci] += ar[ri] * bc[ci];
    }
  }

#pragma unroll
  for (int ri = 0; ri < 8; ri++) {
    long row = rowbase + r0 + ri;
    if (row < Nn) {
      float4 o0 = {acc[ri][0], acc[ri][1], acc[ri][2], acc[ri][3]};
      float4 o1 = {acc[ri][4], acc[ri][5], acc[ri][6], acc[ri][7]};
      *(float4*)&out[row * HD + c0] = o0;
      *(float4*)&out[row * HD + c0 + 4] = o1;
    }
  }
}

__global__ void stats_f32(const float* __restrict__ z, float* stat, int n) {
  int c = threadIdx.x & (HD - 1);
  int rg = threadIdx.x >> 7;
  float s = 0.f, ss = 0.f;
  for (int r = blockIdx.x * 2 + rg; r < n; r += gridDim.x * 2) {
    float v = z[(size_t)r * HD + c];
    s += v; ss += v * v;
  }
  __shared__ float S[2][HD], SS[2][HD];
  S[rg][c] = s; SS[rg][c] = ss;
  __syncthreads();
  if (threadIdx.x < HD) {
    atomicAdd(&stat[c], S[0][c] + S[1][c]);
    atomicAdd(&stat[HD + c], SS[0][c] + SS[1][c]);
  }
}

__global__ void cls_out_kernel(const float* __restrict__ zc, const float* __restrict__ ab,
                               const float* __restrict__ W2, const float* __restrict__ b2,
                               float* out, int G) {
  int row = blockIdx.x;
  int t = threadIdx.x;
  float v0 = fmaxf(zc[(size_t)row * HD + t] * ab[t] + ab[HD + t], 0.f);
  float v1 = fmaxf(zc[(size_t)row * HD + 64 + t] * ab[64 + t] + ab[HD + 64 + t], 0.f);
  for (int o = 0; o < 10; o++) {
    float p = v0 * W2[t * 10 + o] + v1 * W2[(64 + t) * 10 + o];
#pragma unroll
    for (int s = 32; s > 0; s >>= 1) p += __shfl_down(p, s);
    if (t == 0) out[row * 10 + o] = p + b2[o];
  }
}

extern "C" void kernel_launch(void* const* d_in, const int* in_sizes, int n_in,
                              void* d_out, int out_size, void* d_ws, size_t ws_size,
                              hipStream_t stream) {
  const int* x     = (const int*)d_in[0];
  const int* ei    = (const int*)d_in[1];
  const int* batch = (const int*)d_in[2];
  const float* pe  = (const float*)d_in[4];
  const float* ce  = (const float*)d_in[5];
  const float* le  = (const float*)d_in[6];
  const float* cW1 = (const float*)d_in[7];
  const float* cb1 = (const float*)d_in[8];
  const float* cg1 = (const float*)d_in[9];
  const float* cbe1= (const float*)d_in[10];
  const float* cW2 = (const float*)d_in[11];
  const float* cb2 = (const float*)d_in[12];
  const float* ngm = (const float*)d_in[13];
  const float* nbe = (const float*)d_in[14];
  const float* gW1 = (const float*)d_in[15];
  const float* gb1 = (const float*)d_in[16];
  const float* gW2 = (const float*)d_in[17];
  const float* clW1= (const float*)d_in[19];
  const float* clb1= (const float*)d_in[20];
  const float* clg = (const float*)d_in[21];
  const float* clbe= (const float*)d_in[22];
  const float* clW2= (const float*)d_in[23];
  const float* clb2= (const float*)d_in[24];

  int N = in_sizes[2];
  int E = in_sizes[1] / 2;
  int G = out_size / 10;

  float* buf0   = (float*)d_ws;              // h (f32)
  float* buf1   = buf0 + (size_t)N * HD;     // z (f32)
  float* pooled = buf1 + (size_t)N * HD;     // G x 128
  float* gate   = pooled + (size_t)G * HD;   // N
  float* zc     = gate + N;                  // G x 128
  float* stats  = zc + (size_t)G * HD;       // 7 x 1024
  float* ab     = stats + 7 * 1024;          // 7 x 256
  unsigned short* whi = (unsigned short*)(ab + 7 * 256);  // 7 x 128 x 128 bf16
  unsigned short* wlo = whi + 7 * HD * HD;
  unsigned short* hbb = wlo + 7 * HD * HD;   // N x 128 bf16 shadow of h
  int* csr_off  = (int*)(hbb + (size_t)N * HD); // N+1
  int* cursor   = csr_off + (N + 1);         // N
  int* bsum     = cursor + N;                // 128
  int* gs       = bsum + 128;                // G+1
  int* csr_src  = gs + (G + 1);              // E

  float* out = (float*)d_out;
  int gatherBlocks = (N + 127) / 128;
  int splitBlocks  = (N + 63) / 64;
  int Wwin = (N + 7) / 8;

  zero_f<<<28, 256, 0, stream>>>(stats, 7 * 1024);
  encode_kernel<<<2048, 256, 0, stream>>>(x, pe, ce, le, buf0, hbb, N);
  prep_w<<<7, 256, 0, stream>>>(cW1, cW2, gW1, whi, wlo);

  // CSR build (XCD-owned dst windows; reused by all 3 layers)
  int nb = (N + SCAN_BS - 1) / SCAN_BS;
  zero_int<<<256, 256, 0, stream>>>(cursor, N);
  hist_kernel<<<2048, 256, 0, stream>>>(ei, cursor, E, Wwin);
  scan1_kernel<<<nb, 256, 0, stream>>>(cursor, csr_off, bsum, N);
  scan2_kernel<<<1, 128, 0, stream>>>(bsum, nb);
  scan3_kernel<<<256, 256, 0, stream>>>(csr_off, cursor, bsum, N, E);
  fill_kernel<<<2048, 256, 0, stream>>>(ei, cursor, csr_src, E, Wwin);
  bound_kernel<<<(N + 255) / 256, 256, 0, stream>>>(batch, gs, N, G);

  for (int l = 0; l < 3; l++) {
    float* abPrev = ab + (l - 1) * 512 + 256;
    if (l == 0)
      gemm_gather<false, true><<<gatherBlocks, 512, 0, stream>>>(
          buf0, hbb, csr_off, csr_src, nullptr,
          whi + (size_t)l * HD * HD, wlo + (size_t)l * HD * HD,
          cb1 + l * HD, buf1, stats + l * 2048, N);
    else
      gemm_gather<true, true><<<gatherBlocks, 512, 0, stream>>>(
          buf0, hbb, csr_off, csr_src, abPrev,
          whi + (size_t)l * HD * HD, wlo + (size_t)l * HD * HD,
          cb1 + l * HD, buf1, stats + l * 2048, N);
    finalize_kernel<<<1, 128, 0, stream>>>(stats + l * 2048, cg1 + l * HD, cbe1 + l * HD,
                                           ab + l * 512, 1.f / N);
    // z2 -> buf0 (f32) + hbb (bf16 shadow for next layer's gather)
    gemm_split<true, false, true><<<splitBlocks, 512, 0, stream>>>(
        buf1, whi + (size_t)(3 + l) * HD * HD, wlo + (size_t)(3 + l) * HD * HD,
        cb2 + l * HD, ab + l * 512, nullptr, buf0, (l < 2) ? hbb : nullptr,
        nullptr, stats + l * 2048 + 1024, N);
    finalize_kernel<<<1, 128, 0, stream>>>(stats + l * 2048 + 1024, ngm + l * HD, nbe + l * HD,
                                           ab + l * 512 + 256, 1.f / N);
  }

  const float* abFin = ab + 2 * 512 + 256;
  gemm_split<true, true, false><<<splitBlocks, 512, 0, stream>>>(
      buf0, whi + (size_t)6 * HD * HD, wlo + (size_t)6 * HD * HD,
      gb1, abFin, gW2, nullptr, nullptr, gate, nullptr, N);
  fused_pool<<<G, HD, 0, stream>>>(buf0, gate, gs, abFin, pooled);

  // classifier tail in f32
  gemm_f32<<<(G + 127) / 128, 256, 0, stream>>>(pooled, clW1, clb1, zc, G);
  stats_f32<<<64, 256, 0, stream>>>(zc, stats + 6 * 1024, G);
  finalize1_kernel<<<1, 128, 0, stream>>>(stats + 6 * 1024, clg, clbe, ab + 6 * 256, 1.f / G);
  cls_out_kernel<<<G, 64, 0, stream>>>(zc, ab + 6 * 256, clW2, clb2, out, G);
}

// Round 14
// 756.487 us; speedup vs baseline: 1.2253x; 1.0236x over previous
//
#include <hip/hip_runtime.h>
#include <math.h>

#define HD 128

typedef __attribute__((ext_vector_type(8))) short bf16x8;
typedef __attribute__((ext_vector_type(4))) unsigned short us4;
typedef __attribute__((ext_vector_type(4))) float f32x4;

__device__ __forceinline__ float bf2f(unsigned short u) {
  union { unsigned int i; float f; } v; v.i = ((unsigned int)u) << 16; return v.f;
}
__device__ __forceinline__ unsigned short f2bf(float f) {
  union { float f; unsigned int i; } v; v.f = f;
  unsigned int u = v.i;
  u += 0x7FFFu + ((u >> 16) & 1u);
  return (unsigned short)(u >> 16);
}

// compute a=g*invstd, b=be-mean*a from 4-replica stats (col c)
__device__ __forceinline__ void bn_ab(const float* __restrict__ st, const float* __restrict__ g,
                                      const float* __restrict__ be, float inv_n, int c,
                                      float& a, float& b) {
  float s = st[c] + st[256 + c] + st[512 + c] + st[768 + c];
  float sq = st[HD + c] + st[256 + HD + c] + st[512 + HD + c] + st[768 + HD + c];
  float mean = s * inv_n;
  float var = sq * inv_n - mean * mean;
  float inv = rsqrtf(var + 1e-5f);
  a = inv * g[c];
  b = be[c] - mean * a;
}

__global__ void zero_f(float* p, int n) {
  int i = blockIdx.x * blockDim.x + threadIdx.x;
  if (i < n) p[i] = 0.f;
}

__global__ void zero_int(int* p, int n) {
  int stride = gridDim.x * blockDim.x;
  for (int i = blockIdx.x * blockDim.x + threadIdx.x; i < n; i += stride) p[i] = 0;
}

__global__ void encode_kernel(const int* __restrict__ x, const float* __restrict__ pe,
                              const float* __restrict__ ce, const float* __restrict__ le,
                              float* __restrict__ h, unsigned short* __restrict__ hb, int n) {
  int total = n * HD;
  int stride = gridDim.x * blockDim.x;
  for (int idx = blockIdx.x * blockDim.x + threadIdx.x; idx < total; idx += stride) {
    int node = idx >> 7, c = idx & (HD - 1);
    int lv = x[node * 3 + 0]; lv = lv < 0 ? 0 : (lv > 999 ? 999 : lv);
    int ct = x[node * 3 + 1]; ct = ct < 0 ? 0 : (ct > 4 ? 4 : ct);
    int th = x[node * 3 + 2]; th = th < 0 ? 0 : (th > 4999 ? 4999 : th);
    float v = ce[ct * HD + c] + le[lv * HD + c] + pe[th * HD + c];
    h[idx] = v;
    hb[idx] = f2bf(v);
  }
}

// split 7 [128][128] f32 weight mats into bf16 hi/lo in WAVE-TILED fragment layout
__global__ void prep_w(const float* __restrict__ cW1, const float* __restrict__ cW2,
                       const float* __restrict__ gW1,
                       unsigned short* __restrict__ whi, unsigned short* __restrict__ wlo) {
  int m = blockIdx.x;
  const float* W = (m < 3) ? cW1 + (size_t)m * HD * HD
                 : (m < 6) ? cW2 + (size_t)(m - 3) * HD * HD : gW1;
  unsigned short* oh = whi + (size_t)m * HD * HD;
  unsigned short* ol = wlo + (size_t)m * HD * HD;
  for (int i = threadIdx.x; i < HD * HD; i += 256) {
    int j = i & 7;
    int l = (i >> 3) & 63;
    int p = i >> 9;
    int cg = p >> 2, k4 = p & 3;
    int c = cg * 16 + (l & 15);
    int k = (k4 * 4 + (l >> 4)) * 8 + j;
    float f = W[k * HD + c];
    unsigned short hh = f2bf(f);
    oh[i] = hh;
    ol[i] = f2bf(f - bf2f(hh));
  }
}

// ---------------- CSR build (XCD-owned dst windows) -----------------------------

__global__ void hist_kernel(const int* __restrict__ ei, int* deg, int E, int Wwin) {
  int pass = blockIdx.x & 7;
  int b = blockIdx.x >> 3;
  int tstride = (gridDim.x >> 3) * blockDim.x;
  for (int e = b * blockDim.x + threadIdx.x; e < E; e += tstride) {
    int d = ei[E + e];
    if (d / Wwin == pass) atomicAdd(&deg[d], 1);
  }
}

#define SCAN_BS 1024
__global__ void scan1_kernel(const int* __restrict__ deg, int* __restrict__ off,
                             int* __restrict__ bsum, int n) {
  __shared__ int sh[256];
  int b = blockIdx.x, t = threadIdx.x;
  int base = b * SCAN_BS + t * 4;
  int v[4];
#pragma unroll
  for (int j = 0; j < 4; j++) v[j] = (base + j < n) ? deg[base + j] : 0;
  int s = v[0] + v[1] + v[2] + v[3];
  sh[t] = s;
  __syncthreads();
  for (int o = 1; o < 256; o <<= 1) {
    int x = (t >= o) ? sh[t - o] : 0;
    __syncthreads();
    sh[t] += x;
    __syncthreads();
  }
  int excl = sh[t] - s;
  if (t == 255) bsum[b] = sh[255];
  int run = excl;
#pragma unroll
  for (int j = 0; j < 4; j++) {
    if (base + j < n) off[base + j] = run;
    run += v[j];
  }
}

__global__ void scan2_kernel(int* bsum, int nb) {
  __shared__ int sh[128];
  int t = threadIdx.x;
  int v = (t < nb) ? bsum[t] : 0;
  sh[t] = v;
  __syncthreads();
  for (int o = 1; o < 128; o <<= 1) {
    int x = (t >= o) ? sh[t - o] : 0;
    __syncthreads();
    sh[t] += x;
    __syncthreads();
  }
  if (t < nb) bsum[t] = sh[t] - v;
}

__global__ void scan3_kernel(int* off, int* cursor, const int* __restrict__ bsum,
                             int n, int E) {
  int idx = blockIdx.x * blockDim.x + threadIdx.x;
  int stride = gridDim.x * blockDim.x;
  for (int i = idx; i < n; i += stride) {
    int v = off[i] + bsum[i >> 10];
    off[i] = v;
    cursor[i] = v;
  }
  if (idx == 0) off[n] = E;
}

__global__ void fill_kernel(const int* __restrict__ ei, int* cursor, int* csr_src,
                            int E, int Wwin) {
  int pass = blockIdx.x & 7;
  int b = blockIdx.x >> 3;
  int tstride = (gridDim.x >> 3) * blockDim.x;
  for (int e = b * blockDim.x + threadIdx.x; e < E; e += tstride) {
    int d = ei[E + e];
    if (d / Wwin == pass) {
      int pos = atomicAdd(&cursor[d], 1);
      csr_src[pos] = ei[e];
    }
  }
}

// ---------------- fused gather + split-bf16 MFMA GEMM (96-row tile) ------------
// 51 KB LDS -> 3 blocks/CU (1.5x concurrent gather groups vs 128-row tile).
// BN's (a,b) recomputed per block from raw stats (finalize fused away).
// MFMA phase: waves 0-5 each own one full-row 16-row stripe (clean line writes).
template<bool BN, bool STATS>
__global__ __launch_bounds__(512, 6)
void gemm_gather(const float* __restrict__ h, const unsigned short* __restrict__ hb,
                 const int* __restrict__ off, const int* __restrict__ src,
                 const float* __restrict__ statP, const float* __restrict__ gBN,
                 const float* __restrict__ beBN, float inv_n,
                 const unsigned short* __restrict__ Whi,
                 const unsigned short* __restrict__ Wlo,
                 const float* __restrict__ bias, float* __restrict__ outf,
                 float* __restrict__ statOut, int Nn) {
  __shared__ unsigned short XsH[96 * HD];
  __shared__ unsigned short XsL[96 * HD];
  __shared__ float red[2 * HD];
  __shared__ float abl[2 * HD];
  int t = threadIdx.x;
  long rowbase = (long)blockIdx.x * 96;
  int grp = t >> 5, lane = t & 31;

  if (BN) {
    if (t < HD) {
      float a, b;
      bn_ab(statP, gBN, beBN, inv_n, t, a, b);
      abl[t] = a;
      abl[HD + t] = b;
    }
    __syncthreads();
  }

  float4 a4, b4;
  if (BN) {
    a4 = *(const float4*)(abl + lane * 4);
    b4 = *(const float4*)(abl + HD + lane * 4);
  }
#define APPLY_BN(v) if (BN) { \
    v.x = fmaxf(v.x * a4.x + b4.x, 0.f); \
    v.y = fmaxf(v.y * a4.y + b4.y, 0.f); \
    v.z = fmaxf(v.z * a4.z + b4.z, 0.f); \
    v.w = fmaxf(v.w * a4.w + b4.w, 0.f); }
#define UP4(wv) {bf2f(wv[0]), bf2f(wv[1]), bf2f(wv[2]), bf2f(wv[3])}

  // gather phase: 16 groups x 32 lanes; 6 rows/group; 8-deep edge unroll
  for (int rr = 0; rr < 6; rr++) {
    int r = grp + rr * 16;
    long row = rowbase + r; if (row > Nn - 1) row = Nn - 1;
    int s0 = off[row], s1 = off[row + 1];
    float4 acc0 = *(const float4*)(h + row * HD + lane * 4);
    APPLY_BN(acc0);
    float4 acc1 = {0.f, 0.f, 0.f, 0.f};
    float4 acc2 = {0.f, 0.f, 0.f, 0.f};
    float4 acc3 = {0.f, 0.f, 0.f, 0.f};
    int e = s0;
    for (; e + 8 <= s1; e += 8) {
      int i0 = src[e], i1 = src[e + 1], i2 = src[e + 2], i3 = src[e + 3];
      int i4 = src[e + 4], i5 = src[e + 5], i6 = src[e + 6], i7 = src[e + 7];
      us4 w0 = *(const us4*)(hb + (size_t)i0 * HD + lane * 4);
      us4 w1 = *(const us4*)(hb + (size_t)i1 * HD + lane * 4);
      us4 w2 = *(const us4*)(hb + (size_t)i2 * HD + lane * 4);
      us4 w3 = *(const us4*)(hb + (size_t)i3 * HD + lane * 4);
      us4 w4 = *(const us4*)(hb + (size_t)i4 * HD + lane * 4);
      us4 w5 = *(const us4*)(hb + (size_t)i5 * HD + lane * 4);
      us4 w6 = *(const us4*)(hb + (size_t)i6 * HD + lane * 4);
      us4 w7 = *(const us4*)(hb + (size_t)i7 * HD + lane * 4);
      float4 v0 = UP4(w0), v1 = UP4(w1), v2 = UP4(w2), v3 = UP4(w3);
      float4 v4 = UP4(w4), v5 = UP4(w5), v6 = UP4(w6), v7 = UP4(w7);
      APPLY_BN(v0); APPLY_BN(v1); APPLY_BN(v2); APPLY_BN(v3);
      APPLY_BN(v4); APPLY_BN(v5); APPLY_BN(v6); APPLY_BN(v7);
      acc0.x += v0.x + v4.x; acc0.y += v0.y + v4.y; acc0.z += v0.z + v4.z; acc0.w += v0.w + v4.w;
      acc1.x += v1.x + v5.x; acc1.y += v1.y + v5.y; acc1.z += v1.z + v5.z; acc1.w += v1.w + v5.w;
      acc2.x += v2.x + v6.x; acc2.y += v2.y + v6.y; acc2.z += v2.z + v6.z; acc2.w += v2.w + v6.w;
      acc3.x += v3.x + v7.x; acc3.y += v3.y + v7.y; acc3.z += v3.z + v7.z; acc3.w += v3.w + v7.w;
    }
    for (; e < s1; e++) {
      int s = src[e];
      us4 wv = *(const us4*)(hb + (size_t)s * HD + lane * 4);
      float4 v = UP4(wv);
      APPLY_BN(v);
      acc0.x += v.x; acc0.y += v.y; acc0.z += v.z; acc0.w += v.w;
    }
    acc0.x += acc1.x + acc2.x + acc3.x;
    acc0.y += acc1.y + acc2.y + acc3.y;
    acc0.z += acc1.z + acc2.z + acc3.z;
    acc0.w += acc1.w + acc2.w + acc3.w;
    float f[4] = {acc0.x, acc0.y, acc0.z, acc0.w};
    us4 hi, lo;
#pragma unroll
    for (int j = 0; j < 4; j++) {
      unsigned short hh = f2bf(f[j]);
      hi[j] = hh;
      lo[j] = f2bf(f[j] - bf2f(hh));
    }
    int g8 = lane >> 1;
    int offl = r * HD + (((g8 ^ (r & 7)) << 3)) + (lane & 1) * 4;
    *(us4*)(XsH + offl) = hi;
    *(us4*)(XsL + offl) = lo;
  }
#undef APPLY_BN
#undef UP4
  if (STATS && t < 2 * HD) red[t] = 0.f;
  __syncthreads();

  int w = t >> 6, l = t & 63;
  int lr = l & 15, lg = l >> 4;

  if (w < 6) {
    f32x4 acc[8];
#pragma unroll
    for (int ct = 0; ct < 8; ct++) acc[ct] = (f32x4){0.f, 0.f, 0.f, 0.f};

    bf16x8 aH[4], aL[4];
    int arow = w * 16 + lr;
#pragma unroll
    for (int k4 = 0; k4 < 4; k4++) {
      int kg = k4 * 4 + lg;
      int offa = arow * HD + (((kg ^ (arow & 7)) << 3));
      aH[k4] = *(bf16x8*)(XsH + offa);
      aL[k4] = *(bf16x8*)(XsL + offa);
    }
#pragma unroll
    for (int ct = 0; ct < 8; ct++) {
#pragma unroll
      for (int k4 = 0; k4 < 4; k4++) {
        int bo = (((ct << 2) + k4) * 64 + l) * 8;
        bf16x8 bH = *(const bf16x8*)(Whi + bo);
        bf16x8 bL = *(const bf16x8*)(Wlo + bo);
        acc[ct] = __builtin_amdgcn_mfma_f32_16x16x32_bf16(aH[k4], bH, acc[ct], 0, 0, 0);
        acc[ct] = __builtin_amdgcn_mfma_f32_16x16x32_bf16(aH[k4], bL, acc[ct], 0, 0, 0);
        acc[ct] = __builtin_amdgcn_mfma_f32_16x16x32_bf16(aL[k4], bH, acc[ct], 0, 0, 0);
      }
    }

    float s[8], ss[8];
#pragma unroll
    for (int ct = 0; ct < 8; ct++) { s[ct] = 0.f; ss[ct] = 0.f; }
#pragma unroll
    for (int jj = 0; jj < 4; jj++) {
      long row = rowbase + w * 16 + lg * 4 + jj;
      bool ok = row < Nn;
#pragma unroll
      for (int ct = 0; ct < 8; ct++) {
        float v = acc[ct][jj] + bias[ct * 16 + lr];
        if (ok) {
          outf[row * HD + ct * 16 + lr] = v;
          if (STATS) { s[ct] += v; ss[ct] += v * v; }
        }
      }
    }
    if (STATS) {
#pragma unroll
      for (int ct = 0; ct < 8; ct++) {
        float sv = s[ct], sq = ss[ct];
        sv += __shfl_xor(sv, 16); sq += __shfl_xor(sq, 16);
        sv += __shfl_xor(sv, 32); sq += __shfl_xor(sq, 32);
        if (lg == 0) {
          atomicAdd(&red[ct * 16 + lr], sv);
          atomicAdd(&red[HD + ct * 16 + lr], sq);
        }
      }
    }
  }
  if (STATS) {
    __syncthreads();
    float* st = statOut + (blockIdx.x & 3) * 256;
    if (t < 2 * HD) atomicAdd(&st[t], red[t]);
  }
}

// ---------------- split-bf16 MFMA GEMM (contiguous, 64-row tile, 8 waves) ------
template<bool INBN, bool GATE, bool STATS>
__global__ __launch_bounds__(512, 8)
void gemm_split(const float* __restrict__ X, const unsigned short* __restrict__ Whi,
                const unsigned short* __restrict__ Wlo,
                const float* __restrict__ bias,
                const float* __restrict__ statP, const float* __restrict__ gBN,
                const float* __restrict__ beBN, float inv_n,
                const float* __restrict__ w2, float* __restrict__ outf,
                unsigned short* __restrict__ outb,
                float* __restrict__ gate, float* __restrict__ statOut, int Nn) {
  __shared__ unsigned short XsH[64 * HD];
  __shared__ unsigned short XsL[64 * HD];
  __shared__ float red[2 * HD];
  __shared__ float gred[64];
  __shared__ float abl[2 * HD];
  int t = threadIdx.x;
  long rowbase = (long)blockIdx.x * 64;

  if (INBN) {
    if (t < HD) {
      float a, b;
      bn_ab(statP, gBN, beBN, inv_n, t, a, b);
      abl[t] = a;
      abl[HD + t] = b;
    }
  }
  if (STATS && t < 2 * HD) red[t] = 0.f;
  if (GATE && t < 64) gred[t] = 0.f;
  if (INBN) __syncthreads();

#pragma unroll
  for (int it = 0; it < 4; it++) {
    int i = (t + it * 512) * 4;
    int r = i >> 7, k = i & (HD - 1);
    long row = rowbase + r; if (row > Nn - 1) row = Nn - 1;
    float4 v = *(const float4*)(X + row * HD + k);
    float f[4] = {v.x, v.y, v.z, v.w};
    if (INBN) {
#pragma unroll
      for (int j = 0; j < 4; j++)
        f[j] = fmaxf(f[j] * abl[k + j] + abl[HD + k + j], 0.f);
    }
    us4 hi, lo;
#pragma unroll
    for (int j = 0; j < 4; j++) {
      unsigned short hh = f2bf(f[j]);
      hi[j] = hh;
      lo[j] = f2bf(f[j] - bf2f(hh));
    }
    int g = k >> 3;
    int off = r * HD + ((((g ^ (r & 7)) << 3)) | (k & 7));
    *(us4*)(XsH + off) = hi;
    *(us4*)(XsL + off) = lo;
  }
  __syncthreads();

  int w = t >> 6, l = t & 63;
  int lr = l & 15, lg = l >> 4;
  int wr = w & 3, wc = w >> 2;

  f32x4 acc[4];
#pragma unroll
  for (int ct = 0; ct < 4; ct++) acc[ct] = (f32x4){0.f, 0.f, 0.f, 0.f};

  bf16x8 aH[4], aL[4];
  int arow = wr * 16 + lr;
#pragma unroll
  for (int k4 = 0; k4 < 4; k4++) {
    int kg = k4 * 4 + lg;
    int off = arow * HD + (((kg ^ (arow & 7)) << 3));
    aH[k4] = *(bf16x8*)(XsH + off);
    aL[k4] = *(bf16x8*)(XsL + off);
  }
#pragma unroll
  for (int ct = 0; ct < 4; ct++) {
    int cg = wc * 4 + ct;
#pragma unroll
    for (int k4 = 0; k4 < 4; k4++) {
      int bo = (((cg << 2) + k4) * 64 + l) * 8;
      bf16x8 bH = *(const bf16x8*)(Whi + bo);
      bf16x8 bL = *(const bf16x8*)(Wlo + bo);
      acc[ct] = __builtin_amdgcn_mfma_f32_16x16x32_bf16(aH[k4], bH, acc[ct], 0, 0, 0);
      acc[ct] = __builtin_amdgcn_mfma_f32_16x16x32_bf16(aH[k4], bL, acc[ct], 0, 0, 0);
      acc[ct] = __builtin_amdgcn_mfma_f32_16x16x32_bf16(aL[k4], bH, acc[ct], 0, 0, 0);
    }
  }

  if (GATE) {
#pragma unroll
    for (int jj = 0; jj < 4; jj++) {
      float p = 0.f;
#pragma unroll
      for (int ct = 0; ct < 4; ct++) {
        int col = (wc * 4 + ct) * 16 + lr;
        float v = fmaxf(acc[ct][jj] + bias[col], 0.f);
        p += v * w2[col];
      }
      p += __shfl_xor(p, 1);
      p += __shfl_xor(p, 2);
      p += __shfl_xor(p, 4);
      p += __shfl_xor(p, 8);
      if (lr == 0) atomicAdd(&gred[wr * 16 + lg * 4 + jj], p);
    }
    __syncthreads();
    if (t < 64 && rowbase + t < Nn) gate[rowbase + t] = gred[t];
  } else {
    float s[4], ss[4];
#pragma unroll
    for (int ct = 0; ct < 4; ct++) { s[ct] = 0.f; ss[ct] = 0.f; }
#pragma unroll
    for (int jj = 0; jj < 4; jj++) {
      long row = rowbase + wr * 16 + lg * 4 + jj;
      bool ok = row < Nn;
#pragma unroll
      for (int ct = 0; ct < 4; ct++) {
        int col = (wc * 4 + ct) * 16 + lr;
        float v = acc[ct][jj] + bias[col];
        if (ok) {
          outf[row * HD + col] = v;
          if (outb) outb[row * HD + col] = f2bf(v);
          if (STATS) { s[ct] += v; ss[ct] += v * v; }
        }
      }
    }
    if (STATS) {
#pragma unroll
      for (int ct = 0; ct < 4; ct++) {
        int col = (wc * 4 + ct) * 16 + lr;
        float sv = s[ct], sq = ss[ct];
        sv += __shfl_xor(sv, 16); sq += __shfl_xor(sq, 16);
        sv += __shfl_xor(sv, 32); sq += __shfl_xor(sq, 32);
        if (lg == 0) {
          atomicAdd(&red[col], sv);
          atomicAdd(&red[HD + col], sq);
        }
      }
      __syncthreads();
      float* st = statOut + (blockIdx.x & 3) * 256;
      if (t < 2 * HD) atomicAdd(&st[t], red[t]);
    }
  }
}

__global__ void bound_kernel(const int* __restrict__ batch, int* gs, int N, int G) {
  int i = blockIdx.x * blockDim.x + threadIdx.x;
  if (i >= N) return;
  int b = batch[i];
  int prev = (i == 0) ? -1 : batch[i - 1];
  for (int g = prev + 1; g <= b; g++) gs[g] = i;
  if (i == N - 1)
    for (int g = b + 1; g <= G; g++) gs[g] = N;
}

// per-graph softmax pool with deferred BN ((a,b) recomputed from raw stats)
__global__ void fused_pool(const float* __restrict__ h, const float* __restrict__ gate,
                           const int* __restrict__ gs,
                           const float* __restrict__ statP, const float* __restrict__ gBN,
                           const float* __restrict__ beBN, float inv_n,
                           float* __restrict__ pooled) {
  int g = blockIdx.x;
  int t = threadIdx.x;
  int s0 = gs[g], s1 = gs[g + 1];
  if (s0 >= s1) { pooled[(size_t)g * HD + t] = 0.f; return; }
  __shared__ float red[HD];
  float a, b;
  bn_ab(statP, gBN, beBN, inv_n, t, a, b);
  float m = -INFINITY;
  for (int i = s0 + t; i < s1; i += HD) m = fmaxf(m, gate[i]);
  red[t] = m;
  __syncthreads();
  for (int o = 64; o > 0; o >>= 1) {
    if (t < o) red[t] = fmaxf(red[t], red[t + o]);
    __syncthreads();
  }
  m = red[0];
  __syncthreads();
  float s = 0.f;
  for (int i = s0 + t; i < s1; i += HD) s += expf(gate[i] - m);
  red[t] = s;
  __syncthreads();
  for (int o = 64; o > 0; o >>= 1) {
    if (t < o) red[t] += red[t + o];
    __syncthreads();
  }
  float inv = 1.f / red[0];
  float acc = 0.f;
  int i = s0;
  for (; i + 4 <= s1; i += 4) {
    float al0 = expf(gate[i] - m);
    float al1 = expf(gate[i + 1] - m);
    float al2 = expf(gate[i + 2] - m);
    float al3 = expf(gate[i + 3] - m);
    float v0 = fmaxf(h[(size_t)(i + 0) * HD + t] * a + b, 0.f);
    float v1 = fmaxf(h[(size_t)(i + 1) * HD + t] * a + b, 0.f);
    float v2 = fmaxf(h[(size_t)(i + 2) * HD + t] * a + b, 0.f);
    float v3 = fmaxf(h[(size_t)(i + 3) * HD + t] * a + b, 0.f);
    acc += al0 * v0 + al1 * v1 + al2 * v2 + al3 * v3;
  }
  for (; i < s1; i++) {
    float al = expf(gate[i] - m);
    float v = fmaxf(h[(size_t)i * HD + t] * a + b, 0.f);
    acc += al * v;
  }
  pooled[(size_t)g * HD + t] = acc * inv;
}

// f32 classifier GEMM: zc[G x 128] = pooled @ W + bias
__global__ __launch_bounds__(256, 4)
void gemm_f32(const float* __restrict__ X, const float* __restrict__ W,
              const float* __restrict__ bias, float* __restrict__ out, int Nn) {
  __shared__ float XsT[32][132];
  __shared__ float Ws[32][HD];
  int t = threadIdx.x;
  int r0 = (t >> 4) * 8;
  int c0 = (t & 15) * 8;
  long rowbase = (long)blockIdx.x * 128;

  float acc[8][8];
#pragma unroll
  for (int ci = 0; ci < 8; ci++) {
    float bv = bias[c0 + ci];
#pragma unroll
    for (int ri = 0; ri < 8; ri++) acc[ri][ci] = bv;
  }

  int sr = t >> 1;
  int hf = t & 1;
  long srow = rowbase + sr; if (srow > Nn - 1) srow = Nn - 1;
  const float* xrow = X + srow * HD;

  for (int k0 = 0; k0 < HD; k0 += 32) {
    __syncthreads();
#pragma unroll
    for (int j = 0; j < 4; j++) {
      int i = j * 1024 + t * 4;
      int kk = i >> 7, c = i & (HD - 1);
      *(float4*)&Ws[kk][c] = *(const float4*)&W[(size_t)(k0 + kk) * HD + c];
    }
#pragma unroll
    for (int j = 0; j < 4; j++) {
      int kc = k0 + hf * 16 + j * 4;
      float4 v = *(const float4*)&xrow[kc];
      int kl = hf * 16 + j * 4;
      XsT[kl + 0][sr] = v.x;
      XsT[kl + 1][sr] = v.y;
      XsT[kl + 2][sr] = v.z;
      XsT[kl + 3][sr] = v.w;
    }
    __syncthreads();
#pragma unroll 8
    for (int kk = 0; kk < 32; kk++) {
      float4 a0 = *(float4*)&XsT[kk][r0];
      float4 a1 = *(float4*)&XsT[kk][r0 + 4];
      float4 b0 = *(float4*)&Ws[kk][c0];
      float4 b1 = *(float4*)&Ws[kk][c0 + 4];
      float ar[8] = {a0.x, a0.y, a0.z, a0.w, a1.x, a1.y, a1.z, a1.w};
      float bc[8] = {b0.x, b0.y, b0.z, b0.w, b1.x, b1.y, b1.z, b1.w};
#pragma unroll
      for (int ri = 0; ri < 8; ri++)
#pragma unroll
        for (int ci = 0; ci < 8; ci++) acc[ri][ci] += ar[ri] * bc[ci];
    }
  }

#pragma unroll
  for (int ri = 0; ri < 8; ri++) {
    long row = rowbase + r0 + ri;
    if (row < Nn) {
      float4 o0 = {acc[ri][0], acc[ri][1], acc[ri][2], acc[ri][3]};
      float4 o1 = {acc[ri][4], acc[ri][5], acc[ri][6], acc[ri][7]};
      *(float4*)&out[row * HD + c0] = o0;
      *(float4*)&out[row * HD + c0 + 4] = o1;
    }
  }
}

__global__ void stats_f32(const float* __restrict__ z, float* stat, int n) {
  int c = threadIdx.x & (HD - 1);
  int rg = threadIdx.x >> 7;
  float s = 0.f, ss = 0.f;
  for (int r = blockIdx.x * 2 + rg; r < n; r += gridDim.x * 2) {
    float v = z[(size_t)r * HD + c];
    s += v; ss += v * v;
  }
  __shared__ float S[2][HD], SS[2][HD];
  S[rg][c] = s; SS[rg][c] = ss;
  __syncthreads();
  if (threadIdx.x < HD) {
    atomicAdd(&stat[c], S[0][c] + S[1][c]);
    atomicAdd(&stat[HD + c], SS[0][c] + SS[1][c]);
  }
}

// out = relu(bn(zc)) @ W2 + b2; BN (a,b) computed in-register from single-copy stats
__global__ void cls_out_kernel(const float* __restrict__ zc, const float* __restrict__ stat,
                               const float* __restrict__ g, const float* __restrict__ be,
                               float inv_n, const float* __restrict__ W2,
                               const float* __restrict__ b2, float* out, int G) {
  int row = blockIdx.x;
  int t = threadIdx.x;
  float mean0 = stat[t] * inv_n;
  float var0 = stat[HD + t] * inv_n - mean0 * mean0;
  float a0 = rsqrtf(var0 + 1e-5f) * g[t];
  float b0 = be[t] - mean0 * a0;
  float mean1 = stat[64 + t] * inv_n;
  float var1 = stat[HD + 64 + t] * inv_n - mean1 * mean1;
  float a1 = rsqrtf(var1 + 1e-5f) * g[64 + t];
  float b1 = be[64 + t] - mean1 * a1;
  float v0 = fmaxf(zc[(size_t)row * HD + t] * a0 + b0, 0.f);
  float v1 = fmaxf(zc[(size_t)row * HD + 64 + t] * a1 + b1, 0.f);
  for (int o = 0; o < 10; o++) {
    float p = v0 * W2[t * 10 + o] + v1 * W2[(64 + t) * 10 + o];
#pragma unroll
    for (int s = 32; s > 0; s >>= 1) p += __shfl_down(p, s);
    if (t == 0) out[row * 10 + o] = p + b2[o];
  }
}

extern "C" void kernel_launch(void* const* d_in, const int* in_sizes, int n_in,
                              void* d_out, int out_size, void* d_ws, size_t ws_size,
                              hipStream_t stream) {
  const int* x     = (const int*)d_in[0];
  const int* ei    = (const int*)d_in[1];
  const int* batch = (const int*)d_in[2];
  const float* pe  = (const float*)d_in[4];
  const float* ce  = (const float*)d_in[5];
  const float* le  = (const float*)d_in[6];
  const float* cW1 = (const float*)d_in[7];
  const float* cb1 = (const float*)d_in[8];
  const float* cg1 = (const float*)d_in[9];
  const float* cbe1= (const float*)d_in[10];
  const float* cW2 = (const float*)d_in[11];
  const float* cb2 = (const float*)d_in[12];
  const float* ngm = (const float*)d_in[13];
  const float* nbe = (const float*)d_in[14];
  const float* gW1 = (const float*)d_in[15];
  const float* gb1 = (const float*)d_in[16];
  const float* gW2 = (const float*)d_in[17];
  const float* clW1= (const float*)d_in[19];
  const float* clb1= (const float*)d_in[20];
  const float* clg = (const float*)d_in[21];
  const float* clbe= (const float*)d_in[22];
  const float* clW2= (const float*)d_in[23];
  const float* clb2= (const float*)d_in[24];

  int N = in_sizes[2];
  int E = in_sizes[1] / 2;
  int G = out_size / 10;

  float* buf0   = (float*)d_ws;              // h (f32)
  float* buf1   = buf0 + (size_t)N * HD;     // z (f32)
  float* pooled = buf1 + (size_t)N * HD;     // G x 128
  float* gate   = pooled + (size_t)G * HD;   // N
  float* zc     = gate + N;                  // G x 128
  float* stats  = zc + (size_t)G * HD;       // 7 x 1024
  unsigned short* whi = (unsigned short*)(stats + 7 * 1024);  // 7 x 128 x 128 bf16
  unsigned short* wlo = whi + 7 * HD * HD;
  unsigned short* hbb = wlo + 7 * HD * HD;   // N x 128 bf16 shadow of h
  int* csr_off  = (int*)(hbb + (size_t)N * HD); // N+1
  int* cursor   = csr_off + (N + 1);         // N
  int* bsum     = cursor + N;                // 128
  int* gs       = bsum + 128;                // G+1
  int* csr_src  = gs + (G + 1);              // E

  float* out = (float*)d_out;
  int gatherBlocks = (N + 95) / 96;
  int splitBlocks  = (N + 63) / 64;
  int Wwin = (N + 7) / 8;
  float invN = 1.f / N;

  zero_f<<<28, 256, 0, stream>>>(stats, 7 * 1024);
  encode_kernel<<<2048, 256, 0, stream>>>(x, pe, ce, le, buf0, hbb, N);
  prep_w<<<7, 256, 0, stream>>>(cW1, cW2, gW1, whi, wlo);

  // CSR build (XCD-owned dst windows; reused by all 3 layers)
  int nb = (N + SCAN_BS - 1) / SCAN_BS;
  zero_int<<<256, 256, 0, stream>>>(cursor, N);
  hist_kernel<<<2048, 256, 0, stream>>>(ei, cursor, E, Wwin);
  scan1_kernel<<<nb, 256, 0, stream>>>(cursor, csr_off, bsum, N);
  scan2_kernel<<<1, 128, 0, stream>>>(bsum, nb);
  scan3_kernel<<<256, 256, 0, stream>>>(csr_off, cursor, bsum, N, E);
  fill_kernel<<<2048, 256, 0, stream>>>(ei, cursor, csr_src, E, Wwin);
  bound_kernel<<<(N + 255) / 256, 256, 0, stream>>>(batch, gs, N, G);

  for (int l = 0; l < 3; l++) {
    const float* statPrev = stats + (l - 1) * 2048 + 1024;  // layer l-1 second stats
    if (l == 0)
      gemm_gather<false, true><<<gatherBlocks, 512, 0, stream>>>(
          buf0, hbb, csr_off, csr_src, nullptr, nullptr, nullptr, invN,
          whi + (size_t)l * HD * HD, wlo + (size_t)l * HD * HD,
          cb1 + l * HD, buf1, stats + l * 2048, N);
    else
      gemm_gather<true, true><<<gatherBlocks, 512, 0, stream>>>(
          buf0, hbb, csr_off, csr_src, statPrev, ngm + (l - 1) * HD, nbe + (l - 1) * HD, invN,
          whi + (size_t)l * HD * HD, wlo + (size_t)l * HD * HD,
          cb1 + l * HD, buf1, stats + l * 2048, N);
    // z2 -> buf0 (f32) + hbb (bf16 shadow); BN-ab from this layer's first stats
    gemm_split<true, false, true><<<splitBlocks, 512, 0, stream>>>(
        buf1, whi + (size_t)(3 + l) * HD * HD, wlo + (size_t)(3 + l) * HD * HD,
        cb2 + l * HD, stats + l * 2048, cg1 + l * HD, cbe1 + l * HD, invN,
        nullptr, buf0, (l < 2) ? hbb : nullptr, nullptr, stats + l * 2048 + 1024, N);
  }

  const float* statFin = stats + 2 * 2048 + 1024;  // layer-2 second stats
  gemm_split<true, true, false><<<splitBlocks, 512, 0, stream>>>(
      buf0, whi + (size_t)6 * HD * HD, wlo + (size_t)6 * HD * HD,
      gb1, statFin, ngm + 2 * HD, nbe + 2 * HD, invN,
      gW2, nullptr, nullptr, gate, nullptr, N);
  fused_pool<<<G, HD, 0, stream>>>(buf0, gate, gs, statFin, ngm + 2 * HD, nbe + 2 * HD,
                                   invN, pooled);

  // classifier tail in f32
  gemm_f32<<<(G + 127) / 128, 256, 0, stream>>>(pooled, clW1, clb1, zc, G);
  stats_f32<<<64, 256, 0, stream>>>(zc, stats + 6 * 1024, G);
  cls_out_kernel<<<G, 64, 0, stream>>>(zc, stats + 6 * 1024, clg, clbe, 1.f / G,
                                       clW2, clb2, out, G);
}